// Round 3
// baseline (4332.841 us; speedup 1.0000x reference)
//
#include <hip/hip_runtime.h>
#include <hip/hip_bf16.h>

using bf16 = __hip_bfloat16;

__device__ __forceinline__ float b2f(bf16 x){ return __bfloat162float(x); }
__device__ __forceinline__ bf16  f2b(float x){ return __float2bfloat16(x); }

__device__ __forceinline__ float ldf(const float* p){ return *p; }
__device__ __forceinline__ float ldf(const bf16* p){ return __bfloat162float(*p); }

// ---------------------------------------------------------------------------
// Problem dims: B=16, Cin=Cout=C=256, H=W=32, N=HW=1024, Cq=32, T=256
// All device inputs/outputs are fp32 (reference dtype). Intermediates bf16/fp32 in ws.
// ---------------------------------------------------------------------------

// 1) time MLP: te = relu(relu(t @ w1^T + b1) @ w2^T + b2)   [16,256] fp32
__global__ __launch_bounds__(256) void time_mlp_k(
    const float* __restrict__ t, const float* __restrict__ w1, const float* __restrict__ b1,
    const float* __restrict__ w2, const float* __restrict__ b2, float* __restrict__ te)
{
    const int b = blockIdx.x, j = threadIdx.x;
    __shared__ float tr[256], hid[256];
    tr[j] = t[(b << 8) + j];
    __syncthreads();
    float s = b1[j];
    const float* wp = w1 + j * 256;
    for (int k = 0; k < 256; ++k) s += tr[k] * wp[k];
    hid[j] = fmaxf(s, 0.f);
    __syncthreads();
    float s2 = b2[j];
    const float* wp2 = w2 + j * 256;
    for (int k = 0; k < 256; ++k) s2 += hid[k] * wp2[k];
    te[(b << 8) + j] = fmaxf(s2, 0.f);
}

// 2) conv3x3 SAME (+bias, optional relu). One block per (b, co); stages each
//    input plane (34x34 w/ zero halo) in LDS, loops ci.
template<bool RELU, typename Tin>
__global__ __launch_bounds__(256) void conv3x3_k(
    const Tin* __restrict__ in, const float* __restrict__ w,
    const float* __restrict__ bias, bf16* __restrict__ out)
{
    const int bc = blockIdx.x;
    const int b = bc >> 8, co = bc & 255;
    __shared__ float xs[34][35];
    __shared__ float ws9[9];
    const int tid = threadIdx.x;
    const int h0 = tid >> 5;   // 0..7
    const int w0 = tid & 31;   // 0..31
    float acc[4] = {0.f, 0.f, 0.f, 0.f};

    for (int ci = 0; ci < 256; ++ci) {
        const Tin* xp = in + (size_t)((b << 8) + ci) * 1024;
        for (int i = tid; i < 34 * 34; i += 256) {
            const int r = i / 34, c = i - r * 34;
            const int gr = r - 1, gc = c - 1;
            float v = 0.f;
            if ((unsigned)gr < 32u && (unsigned)gc < 32u) v = ldf(xp + gr * 32 + gc);
            xs[r][c] = v;
        }
        if (tid < 9) ws9[tid] = w[(size_t)((co << 8) + ci) * 9 + tid];
        __syncthreads();
        #pragma unroll
        for (int k = 0; k < 4; ++k) {
            const int hh = h0 + k * 8;
            float s = xs[hh + 0][w0 + 0] * ws9[0] + xs[hh + 0][w0 + 1] * ws9[1] + xs[hh + 0][w0 + 2] * ws9[2]
                    + xs[hh + 1][w0 + 0] * ws9[3] + xs[hh + 1][w0 + 1] * ws9[4] + xs[hh + 1][w0 + 2] * ws9[5]
                    + xs[hh + 2][w0 + 0] * ws9[6] + xs[hh + 2][w0 + 1] * ws9[7] + xs[hh + 2][w0 + 2] * ws9[8];
            acc[k] += s;
        }
        __syncthreads();
    }
    const float bia = bias[co];
    bf16* op = out + (size_t)((b << 8) + co) * 1024;
    #pragma unroll
    for (int k = 0; k < 4; ++k) {
        float v = acc[k] + bia;
        if (RELU) v = fmaxf(v, 0.f);
        op[(h0 + k * 8) * 32 + w0] = f2b(v);
    }
}

// 3) batchnorm stats per channel over (B,H,W): scale=g/sqrt(var+eps), shift=b-mean*scale
__global__ __launch_bounds__(256) void bn_stats_k(
    const bf16* __restrict__ a, const float* __restrict__ g, const float* __restrict__ bb,
    float* __restrict__ scale, float* __restrict__ shift)
{
    const int c = blockIdx.x, tid = threadIdx.x;
    float s = 0.f, sq = 0.f;
    for (int b = 0; b < 16; ++b) {
        const bf16* p = a + (size_t)((b << 8) + c) * 1024;
        for (int n = tid; n < 1024; n += 256) {
            const float v = b2f(p[n]);
            s += v; sq += v * v;
        }
    }
    __shared__ float rs[256], rq[256];
    rs[tid] = s; rq[tid] = sq;
    __syncthreads();
    for (int o = 128; o > 0; o >>= 1) {
        if (tid < o) { rs[tid] += rs[tid + o]; rq[tid] += rq[tid + o]; }
        __syncthreads();
    }
    if (tid == 0) {
        const float m = rs[0] * (1.f / 16384.f);
        const float var = rq[0] * (1.f / 16384.f) - m * m;
        const float inv = rsqrtf(var + 1e-5f);
        const float sc = g[c] * inv;
        scale[c] = sc;
        shift[c] = bb[c] - m * sc;
    }
}

// 4) bn apply (+ optional time-embedding broadcast add)
__global__ __launch_bounds__(256) void bn_apply_k(
    const bf16* __restrict__ a, const float* __restrict__ scale, const float* __restrict__ shift,
    const float* __restrict__ te, bf16* __restrict__ out)
{
    const int idx = blockIdx.x * 256 + threadIdx.x;   // 4194304 total
    const int c = (idx >> 10) & 255;
    const int b = idx >> 18;
    float v = scale[c] * b2f(a[idx]) + shift[c];
    if (te) v += te[(b << 8) + c];
    out[idx] = f2b(v);
}

// 5) QKV projections from y [B,C,N]. One block per (b, 32-col n-tile).
__global__ __launch_bounds__(256) void qkv_k(
    const bf16* __restrict__ y,
    const float* __restrict__ wq, const float* __restrict__ bq,
    const float* __restrict__ wk, const float* __restrict__ bk,
    const float* __restrict__ wv, const float* __restrict__ bv,
    float* __restrict__ Q, float* __restrict__ K, bf16* __restrict__ V)
{
    const int b  = blockIdx.x >> 5;
    const int n0 = (blockIdx.x & 31) << 5;
    __shared__ float ys[256][33];
    const int tid = threadIdx.x;
    {
        const bf16* yp = y + (size_t)((b << 8) + tid) * 1024 + n0;
        #pragma unroll
        for (int j = 0; j < 32; ++j) ys[tid][j] = b2f(yp[j]);
    }
    __syncthreads();

    // Q [B,N,Cq] and K [B,Cq,N]
    const int q  = tid & 31;
    const int nb = tid >> 5;  // 0..7
    const float bqv = bq[q];
    const float bkv = bk[q];
    const float* wqp = wq + q * 256;
    const float* wkp = wk + q * 256;
    #pragma unroll
    for (int k = 0; k < 4; ++k) {
        const int nn = nb + 8 * k;
        float sq_ = bqv, sk_ = bkv;
        for (int c = 0; c < 256; ++c) {
            const float yv = ys[c][nn];
            sq_ += wqp[c] * yv;
            sk_ += wkp[c] * yv;
        }
        Q[(size_t)((b << 10) + n0 + nn) * 32 + q] = sq_;
        K[(size_t)((b << 5) + q) * 1024 + n0 + nn] = sk_;
    }

    // V [B,C,N]
    const int nn2 = tid & 31;
    for (int k = 0; k < 32; ++k) {
        const int v = (tid >> 5) + 8 * k;
        float s = bv[v];
        const float* wvp = wv + v * 256;
        for (int c = 0; c < 256; ++c) s += wvp[c] * ys[c][nn2];
        V[(size_t)((b << 8) + v) * 1024 + n0 + nn2] = f2b(s);
    }
}

// 6) fused scores + softmax: one block per (b, n) row; attn stored bf16
__global__ __launch_bounds__(256) void attn_k(
    const float* __restrict__ Q, const float* __restrict__ K, bf16* __restrict__ attn)
{
    const int b = blockIdx.x >> 10;
    const int n = blockIdx.x & 1023;
    __shared__ float qs[32];
    __shared__ float red[256];
    const int tid = threadIdx.x;
    if (tid < 32) qs[tid] = Q[(size_t)((b << 10) + n) * 32 + tid];
    __syncthreads();

    float s[4];
    #pragma unroll
    for (int k = 0; k < 4; ++k) {
        const int m = tid + (k << 8);
        float acc = 0.f;
        #pragma unroll
        for (int q = 0; q < 32; ++q) acc += qs[q] * K[(size_t)((b << 5) + q) * 1024 + m];
        s[k] = acc;
    }
    float mx = fmaxf(fmaxf(s[0], s[1]), fmaxf(s[2], s[3]));
    red[tid] = mx; __syncthreads();
    for (int o = 128; o > 0; o >>= 1) {
        if (tid < o) red[tid] = fmaxf(red[tid], red[tid + o]);
        __syncthreads();
    }
    mx = red[0]; __syncthreads();
    float sum = 0.f;
    #pragma unroll
    for (int k = 0; k < 4; ++k) { s[k] = expf(s[k] - mx); sum += s[k]; }
    red[tid] = sum; __syncthreads();
    for (int o = 128; o > 0; o >>= 1) {
        if (tid < o) red[tid] += red[tid + o];
        __syncthreads();
    }
    const float inv = 1.f / red[0];
    #pragma unroll
    for (int k = 0; k < 4; ++k)
        attn[(size_t)((b << 10) + n) * 1024 + tid + (k << 8)] = f2b(s[k] * inv);
}

// 7) PV + residual: out = gamma * (V @ attn^T) + y. 64x64 output tile/block. out fp32.
__global__ __launch_bounds__(256) void pv_k(
    const bf16* __restrict__ V, const bf16* __restrict__ attn,
    const bf16* __restrict__ y, const float* __restrict__ gamma, float* __restrict__ out)
{
    const int blk = blockIdx.x;
    const int b  = blk >> 6;
    const int c0 = ((blk >> 4) & 3) * 64;
    const int n0 = (blk & 15) * 64;
    __shared__ float Vt[64][33], At[64][33];
    const int tid = threadIdx.x;
    const int tc = tid >> 4, tn = tid & 15;
    float acc[4][4] = {{0.f}};

    for (int m0 = 0; m0 < 1024; m0 += 32) {
        const int r = tid >> 2, cs = (tid & 3) * 8;
        const bf16* vp = V    + (size_t)((b << 8) + c0 + r) * 1024 + m0 + cs;
        const bf16* ap = attn + (size_t)((b << 10) + n0 + r) * 1024 + m0 + cs;
        #pragma unroll
        for (int j = 0; j < 8; ++j) Vt[r][cs + j] = b2f(vp[j]);
        #pragma unroll
        for (int j = 0; j < 8; ++j) At[r][cs + j] = b2f(ap[j]);
        __syncthreads();
        for (int mm = 0; mm < 32; ++mm) {
            float vv[4], aa[4];
            #pragma unroll
            for (int i = 0; i < 4; ++i) vv[i] = Vt[tc * 4 + i][mm];
            #pragma unroll
            for (int j = 0; j < 4; ++j) aa[j] = At[tn * 4 + j][mm];
            #pragma unroll
            for (int i = 0; i < 4; ++i)
                #pragma unroll
                for (int j = 0; j < 4; ++j) acc[i][j] += vv[i] * aa[j];
        }
        __syncthreads();
    }
    const float g = gamma[0];
    #pragma unroll
    for (int i = 0; i < 4; ++i) {
        const int c = c0 + tc * 4 + i;
        #pragma unroll
        for (int j = 0; j < 4; ++j) {
            const int n = n0 + tn * 4 + j;
            const size_t idx = (size_t)((b << 8) + c) * 1024 + n;
            out[idx] = g * acc[i][j] + b2f(y[idx]);
        }
    }
}

// ---------------------------------------------------------------------------
// Workspace layout (54.6 MB total):
//   [0,16K)      te (fp32)
//   [16K,32K)    bn scale/shift (fp32)
//   base = 32K:
//   [base, +2M)   Q  fp32
//   [+2M, +4M)    K  fp32
//   [+4M, +12M)   Y  bf16
//   [+12M,+20M)   V  bf16
//   [+20M,+28M)   A  bf16   \ dead after qkv_k;
//   [+28M,+36M)   H  bf16   / attn (32 MB bf16) aliases [+20M,+52M)
// ---------------------------------------------------------------------------
extern "C" void kernel_launch(void* const* d_in, const int* in_sizes, int n_in,
                              void* d_out, int out_size, void* d_ws, size_t ws_size,
                              hipStream_t stream)
{
    const float* x     = (const float*)d_in[0];
    const float* t     = (const float*)d_in[1];
    const float* w_t1  = (const float*)d_in[2];
    const float* b_t1  = (const float*)d_in[3];
    const float* w_t2  = (const float*)d_in[4];
    const float* b_t2  = (const float*)d_in[5];
    const float* w_c1  = (const float*)d_in[6];
    const float* b_c1  = (const float*)d_in[7];
    const float* w_c2  = (const float*)d_in[8];
    const float* b_c2  = (const float*)d_in[9];
    const float* w_tr  = (const float*)d_in[10];
    const float* b_tr  = (const float*)d_in[11];
    const float* bn1g  = (const float*)d_in[12];
    const float* bn1b  = (const float*)d_in[13];
    const float* bn2g  = (const float*)d_in[14];
    const float* bn2b  = (const float*)d_in[15];
    const float* wq    = (const float*)d_in[16];
    const float* bq    = (const float*)d_in[17];
    const float* wk    = (const float*)d_in[18];
    const float* bk    = (const float*)d_in[19];
    const float* wv    = (const float*)d_in[20];
    const float* bv    = (const float*)d_in[21];
    const float* gamma = (const float*)d_in[22];
    float* out = (float*)d_out;

    char* ws = (char*)d_ws;
    const size_t MB = 1048576;
    float* te     = (float*)(ws + 0);
    float* scale1 = (float*)(ws + 16384);
    float* shift1 = scale1 + 256;
    float* scale2 = shift1 + 256;
    float* shift2 = scale2 + 256;
    char*  base   = ws + 32768;
    float* Q      = (float*)(base);               // 2 MB
    float* K      = (float*)(base + 2 * MB);      // 2 MB
    bf16*  Y      = (bf16*)(base + 4 * MB);       // 8 MB
    bf16*  V      = (bf16*)(base + 12 * MB);      // 8 MB
    bf16*  A      = (bf16*)(base + 20 * MB);      // 8 MB (dead after qkv_k)
    bf16*  H      = (bf16*)(base + 28 * MB);      // 8 MB (dead after qkv_k)
    bf16*  attn   = (bf16*)(base + 20 * MB);      // 32 MB, aliases A+H+tail

    time_mlp_k<<<16, 256, 0, stream>>>(t, w_t1, b_t1, w_t2, b_t2, te);
    conv3x3_k<true , float><<<4096, 256, 0, stream>>>(x, w_c1, b_c1, A);
    bn_stats_k<<<256, 256, 0, stream>>>(A, bn1g, bn1b, scale1, shift1);
    bn_apply_k<<<16384, 256, 0, stream>>>(A, scale1, shift1, te, H);
    conv3x3_k<true , bf16 ><<<4096, 256, 0, stream>>>(H, w_c2, b_c2, A);
    bn_stats_k<<<256, 256, 0, stream>>>(A, bn2g, bn2b, scale2, shift2);
    bn_apply_k<<<16384, 256, 0, stream>>>(A, scale2, shift2, nullptr, H);
    conv3x3_k<false, bf16 ><<<4096, 256, 0, stream>>>(H, w_tr, b_tr, Y);
    qkv_k<<<512, 256, 0, stream>>>(Y, wq, bq, wk, bk, wv, bv, Q, K, V);
    attn_k<<<16384, 256, 0, stream>>>(Q, K, attn);
    pv_k<<<1024, 256, 0, stream>>>(V, attn, Y, gamma, out);
}

// Round 4
// 717.710 us; speedup vs baseline: 6.0370x; 6.0370x over previous
//
#include <hip/hip_runtime.h>
#include <hip/hip_bf16.h>

using bf16 = __hip_bfloat16;

typedef __attribute__((ext_vector_type(8))) short bf16x8_t;
typedef __attribute__((ext_vector_type(4))) float f32x4_t;

__device__ __forceinline__ float b2f(bf16 x){ return __bfloat162float(x); }
__device__ __forceinline__ bf16  f2b(float x){ return __float2bfloat16(x); }
__device__ __forceinline__ unsigned short f2bu(float x){ bf16 h = __float2bfloat16(x); return *(unsigned short*)&h; }
__device__ __forceinline__ float bits2f(unsigned int lo16){ return __uint_as_float(lo16 << 16); }

__device__ __forceinline__ void gload16(const void* g, void* l) {
    __builtin_amdgcn_global_load_lds(
        (const __attribute__((address_space(1))) unsigned int*)g,
        (__attribute__((address_space(3))) unsigned int*)l, 16, 0, 0);
}

// ---------------------------------------------------------------------------
// Dims: B=16, C=256, H=W=32, N=1024, padded P=34x34=1156, K=9*256=2304
// ---------------------------------------------------------------------------

__global__ void zero_k(unsigned int* __restrict__ p, unsigned int n) {
    for (unsigned int i = blockIdx.x * 256 + threadIdx.x; i < n; i += gridDim.x * 256) p[i] = 0u;
}

// time MLP (unchanged)
__global__ __launch_bounds__(256) void time_mlp_k(
    const float* __restrict__ t, const float* __restrict__ w1, const float* __restrict__ b1,
    const float* __restrict__ w2, const float* __restrict__ b2, float* __restrict__ te)
{
    const int b = blockIdx.x, j = threadIdx.x;
    __shared__ float tr[256], hid[256];
    tr[j] = t[(b << 8) + j];
    __syncthreads();
    float s = b1[j];
    const float* wp = w1 + j * 256;
    for (int k = 0; k < 256; ++k) s += tr[k] * wp[k];
    hid[j] = fmaxf(s, 0.f);
    __syncthreads();
    float s2 = b2[j];
    const float* wp2 = w2 + j * 256;
    for (int k = 0; k < 256; ++k) s2 += hid[k] * wp2[k];
    te[(b << 8) + j] = fmaxf(s2, 0.f);
}

// weights [co][ci][3][3] fp32 -> W3 [co][off][ci] bf16
__global__ __launch_bounds__(256) void prep_w_k(const float* __restrict__ w, bf16* __restrict__ W3)
{
    const int blk = blockIdx.x;            // co*9 + off
    const int ci = threadIdx.x;
    const int co = blk / 9, off = blk % 9;
    W3[(size_t)blk * 256 + ci] = f2b(w[(size_t)co * 2304 + ci * 9 + off]);
}

// x fp32 [b][c][n] -> Xp bf16 [b][1156][c] (interior only; halo pre-zeroed)
__global__ __launch_bounds__(256) void prep_x_k(const float* __restrict__ x, bf16* __restrict__ Xp)
{
    __shared__ float xs[64][65];
    const int t = threadIdx.x;
    const int b = blockIdx.x >> 6, ct = (blockIdx.x >> 4) & 3, nt = blockIdx.x & 15;
    const int c0 = ct << 6, n0 = nt << 6;
    {
        const int cl = t >> 2, nc = (t & 3) << 4;
        const float* src = x + (size_t)((b << 8) + c0 + cl) * 1024 + n0 + nc;
        #pragma unroll
        for (int j = 0; j < 16; j += 4) {
            const float4 v = *(const float4*)(src + j);
            xs[cl][nc + j] = v.x; xs[cl][nc + j + 1] = v.y;
            xs[cl][nc + j + 2] = v.z; xs[cl][nc + j + 3] = v.w;
        }
    }
    __syncthreads();
    {
        const int nl = t >> 2, cc = (t & 3) << 4;
        const int n = n0 + nl;
        const int p = ((n >> 5) + 1) * 34 + (n & 31) + 1;
        unsigned int u[8];
        #pragma unroll
        for (int k = 0; k < 8; ++k)
            u[k] = (unsigned int)f2bu(xs[cc + 2 * k][nl]) | ((unsigned int)f2bu(xs[cc + 2 * k + 1][nl]) << 16);
        bf16* dst = Xp + (size_t)(b * 1156 + p) * 256 + c0 + cc;
        *(uint4*)dst = make_uint4(u[0], u[1], u[2], u[3]);
        *(uint4*)(dst + 8) = make_uint4(u[4], u[5], u[6], u[7]);
    }
}

// conv3x3 as implicit GEMM via MFMA. Xp [b][1156][256] bf16, W3 [256][9][256] bf16.
// Output pixel-major Craw [b][1024][256] bf16 (+bias, optional relu).
template<bool RELU>
__global__ __launch_bounds__(256, 1) void conv_mfma_k(
    const bf16* __restrict__ Xp, const bf16* __restrict__ W3,
    const float* __restrict__ bias, bf16* __restrict__ outp)
{
    __shared__ bf16 Als[128 * 64];   // pixels x k(64), rows 128B, XOR-swizzled 16B slots
    __shared__ bf16 Bls[128 * 64];   // co x k(64)
    const int tid = threadIdx.x;
    const int wid = tid >> 6, lane = tid & 63;
    const int wm = wid >> 1, wn = wid & 1;
    const int blk = blockIdx.x;
    const int b = blk >> 4, mt = (blk >> 1) & 7, nt = blk & 1;
    const int m0 = mt << 7, co0 = nt << 7;

    // staging constants: instr i covers rows wid*32+i*8 .. +8; lane l -> row +(l>>3), slot l&7
    const int srow = (wid << 5) + (lane >> 3);
    const int sL8 = (((lane & 7) ^ (lane >> 3)) << 3);   // swizzled logical k-offset (elements)

    const bf16* agp[4]; const bf16* bgp[4];
    bf16* aldst[4]; bf16* bldst[4];
    #pragma unroll
    for (int i = 0; i < 4; ++i) {
        const int r = srow + i * 8;
        const int n = m0 + r;
        const int pb = (n >> 5) * 34 + (n & 31);
        agp[i] = Xp + (size_t)(b * 1156 + pb) * 256 + sL8;
        bgp[i] = W3 + (size_t)(co0 + r) * 2304 + sL8;
        aldst[i] = Als + ((wid << 5) + i * 8) * 64;
        bldst[i] = Bls + ((wid << 5) + i * 8) * 64;
    }

    // ds_read constants: row = base + (lane&15); phys slot = (kh*4 + lane>>4) ^ (row&7)
    const int rsel = lane & 15;
    const int s0 = (((lane >> 4) ^ (lane & 7)) << 3);
    const int s1 = ((((lane >> 4) + 4) ^ (lane & 7)) << 3);
    const int arow = ((wm << 6) + rsel) << 6;
    const int brow = ((wn << 6) + rsel) << 6;

    f32x4_t acc[4][4];
    #pragma unroll
    for (int mi = 0; mi < 4; ++mi)
        #pragma unroll
        for (int ni = 0; ni < 4; ++ni)
            acc[mi][ni] = (f32x4_t){0.f, 0.f, 0.f, 0.f};

    int kt = 0;
    for (int off = 0; off < 9; ++off) {
        const int kh3 = (off * 11) >> 5;         // off/3
        const int doff = (off + 31 * kh3) << 8;  // (kh*34+kw)*256
        const int koff0 = off << 8;
        for (int cic = 0; cic < 4; ++cic, ++kt) {
            if (kt) __syncthreads();
            const int k64 = cic << 6;
            #pragma unroll
            for (int i = 0; i < 4; ++i) {
                gload16(agp[i] + doff + k64, aldst[i]);
                gload16(bgp[i] + koff0 + k64, bldst[i]);
            }
            __syncthreads();   // waitcnt drain before barrier => LDS valid
            #pragma unroll
            for (int kh = 0; kh < 2; ++kh) {
                const int sk = kh ? s1 : s0;
                bf16x8_t av[4], bv[4];
                #pragma unroll
                for (int mi = 0; mi < 4; ++mi)
                    av[mi] = *(const bf16x8_t*)(Als + arow + (mi << 10) + sk);
                #pragma unroll
                for (int ni = 0; ni < 4; ++ni)
                    bv[ni] = *(const bf16x8_t*)(Bls + brow + (ni << 10) + sk);
                #pragma unroll
                for (int mi = 0; mi < 4; ++mi)
                    #pragma unroll
                    for (int ni = 0; ni < 4; ++ni)
                        acc[mi][ni] = __builtin_amdgcn_mfma_f32_16x16x32_bf16(
                            av[mi], bv[ni], acc[mi][ni], 0, 0, 0);
            }
        }
    }

    // epilogue: C frag row=(lane>>4)*4+j (pixel), col=lane&15 (co)
    const int cr = (lane >> 4) << 2;
    const int cc = lane & 15;
    #pragma unroll
    for (int ni = 0; ni < 4; ++ni) {
        const int co = co0 + (wn << 6) + (ni << 4) + cc;
        const float bb = bias[co];
        #pragma unroll
        for (int mi = 0; mi < 4; ++mi) {
            const int n = m0 + (wm << 6) + (mi << 4) + cr;
            #pragma unroll
            for (int j = 0; j < 4; ++j) {
                float v = acc[mi][ni][j] + bb;
                if (RELU) v = fmaxf(v, 0.f);
                outp[(size_t)((b << 10) + n + j) * 256 + co] = f2b(v);
            }
        }
    }
}

// bn stats over pixel-major Craw [16384][256]: atomic partial sums -> sums[512]
__global__ __launch_bounds__(256) void bn_stats_T_k(
    const bf16* __restrict__ a, float* __restrict__ sums)
{
    __shared__ float ls[256], lq[256];
    const int t = threadIdx.x;
    ls[t] = 0.f; lq[t] = 0.f;
    __syncthreads();
    const int g = t >> 5, c0 = (t & 31) << 3;
    float s[8] = {0,0,0,0,0,0,0,0}, q[8] = {0,0,0,0,0,0,0,0};
    const int rbase = blockIdx.x * 64;
    for (int rr = g; rr < 64; rr += 8) {
        const uint4 u = *(const uint4*)(a + (size_t)(rbase + rr) * 256 + c0);
        const unsigned int w[4] = {u.x, u.y, u.z, u.w};
        #pragma unroll
        for (int k = 0; k < 4; ++k) {
            const float v0 = bits2f(w[k] & 0xffffu);
            const float v1 = __uint_as_float(w[k] & 0xffff0000u);
            s[2 * k] += v0; q[2 * k] += v0 * v0;
            s[2 * k + 1] += v1; q[2 * k + 1] += v1 * v1;
        }
    }
    #pragma unroll
    for (int j = 0; j < 8; ++j) {
        atomicAdd(&ls[c0 + j], s[j]);
        atomicAdd(&lq[c0 + j], q[j]);
    }
    __syncthreads();
    atomicAdd(&sums[t], ls[t]);
    atomicAdd(&sums[256 + t], lq[t]);
}

__global__ __launch_bounds__(256) void bn_fin_k(
    const float* __restrict__ sums, const float* __restrict__ g, const float* __restrict__ bb,
    float* __restrict__ scale, float* __restrict__ shift)
{
    const int c = threadIdx.x;
    const float m = sums[c] * (1.f / 16384.f);
    const float var = sums[256 + c] * (1.f / 16384.f) - m * m;
    const float sc = g[c] * rsqrtf(var + 1e-5f);
    scale[c] = sc; shift[c] = bb[c] - m * sc;
}

// bn apply on pixel-major rows; writes padded-transposed Xp interior (pure row-remap)
template<bool TE>
__global__ __launch_bounds__(256) void bn_apply_T_k(
    const bf16* __restrict__ a, const float* __restrict__ scale,
    const float* __restrict__ shift, const float* __restrict__ te,
    bf16* __restrict__ Xp)
{
    const int t = threadIdx.x;
    const int row = blockIdx.x * 8 + (t >> 5);
    const int c0 = (t & 31) << 3;
    const int b = row >> 10, n = row & 1023;
    const uint4 u = *(const uint4*)(a + (size_t)row * 256 + c0);
    const unsigned int w[4] = {u.x, u.y, u.z, u.w};
    const float4 sc0 = *(const float4*)(scale + c0);
    const float4 sc1 = *(const float4*)(scale + c0 + 4);
    const float4 sh0 = *(const float4*)(shift + c0);
    const float4 sh1 = *(const float4*)(shift + c0 + 4);
    const float scv[8] = {sc0.x, sc0.y, sc0.z, sc0.w, sc1.x, sc1.y, sc1.z, sc1.w};
    const float shv[8] = {sh0.x, sh0.y, sh0.z, sh0.w, sh1.x, sh1.y, sh1.z, sh1.w};
    float tev[8] = {0,0,0,0,0,0,0,0};
    if (TE) {
        const float4 t0 = *(const float4*)(te + (b << 8) + c0);
        const float4 t1 = *(const float4*)(te + (b << 8) + c0 + 4);
        tev[0]=t0.x; tev[1]=t0.y; tev[2]=t0.z; tev[3]=t0.w;
        tev[4]=t1.x; tev[5]=t1.y; tev[6]=t1.z; tev[7]=t1.w;
    }
    unsigned int o[4];
    #pragma unroll
    for (int k = 0; k < 4; ++k) {
        const float v0 = bits2f(w[k] & 0xffffu) * scv[2*k] + shv[2*k] + tev[2*k];
        const float v1 = __uint_as_float(w[k] & 0xffff0000u) * scv[2*k+1] + shv[2*k+1] + tev[2*k+1];
        o[k] = (unsigned int)f2bu(v0) | ((unsigned int)f2bu(v1) << 16);
    }
    const int p = ((n >> 5) + 1) * 34 + (n & 31) + 1;
    *(uint4*)(Xp + (size_t)(b * 1156 + p) * 256 + c0) = make_uint4(o[0], o[1], o[2], o[3]);
}

// Yt [b][n][c] -> Y [b][c][n] (for the legacy attention path)
__global__ __launch_bounds__(256) void transpose_Y_k(
    const bf16* __restrict__ Yt, bf16* __restrict__ Y)
{
    __shared__ float xs[64][65];
    const int t = threadIdx.x;
    const int b = blockIdx.x >> 6, ct = (blockIdx.x >> 4) & 3, nt = blockIdx.x & 15;
    const int c0 = ct << 6, n0 = nt << 6;
    {
        const int nl = t >> 2, cc = (t & 3) << 4;
        const bf16* src = Yt + (size_t)((b << 10) + n0 + nl) * 256 + c0 + cc;
        const uint4 u0 = *(const uint4*)src;
        const uint4 u1 = *(const uint4*)(src + 8);
        const unsigned int w[8] = {u0.x, u0.y, u0.z, u0.w, u1.x, u1.y, u1.z, u1.w};
        #pragma unroll
        for (int k = 0; k < 8; ++k) {
            xs[cc + 2 * k][nl] = bits2f(w[k] & 0xffffu);
            xs[cc + 2 * k + 1][nl] = __uint_as_float(w[k] & 0xffff0000u);
        }
    }
    __syncthreads();
    {
        const int cl = t >> 2, nc = (t & 3) << 4;
        unsigned int o[8];
        #pragma unroll
        for (int k = 0; k < 8; ++k)
            o[k] = (unsigned int)f2bu(xs[cl][nc + 2 * k]) | ((unsigned int)f2bu(xs[cl][nc + 2 * k + 1]) << 16);
        bf16* dst = Y + (size_t)((b << 8) + c0 + cl) * 1024 + n0 + nc;
        *(uint4*)dst = make_uint4(o[0], o[1], o[2], o[3]);
        *(uint4*)(dst + 8) = make_uint4(o[4], o[5], o[6], o[7]);
    }
}

// ---- legacy attention path (unchanged from round 3) ----
__global__ __launch_bounds__(256) void qkv_k(
    const bf16* __restrict__ y,
    const float* __restrict__ wq, const float* __restrict__ bq,
    const float* __restrict__ wk, const float* __restrict__ bk,
    const float* __restrict__ wv, const float* __restrict__ bv,
    float* __restrict__ Q, float* __restrict__ K, bf16* __restrict__ V)
{
    const int b  = blockIdx.x >> 5;
    const int n0 = (blockIdx.x & 31) << 5;
    __shared__ float ys[256][33];
    const int tid = threadIdx.x;
    {
        const bf16* yp = y + (size_t)((b << 8) + tid) * 1024 + n0;
        #pragma unroll
        for (int j = 0; j < 32; ++j) ys[tid][j] = b2f(yp[j]);
    }
    __syncthreads();
    const int q  = tid & 31;
    const int nb = tid >> 5;
    const float bqv = bq[q];
    const float bkv = bk[q];
    const float* wqp = wq + q * 256;
    const float* wkp = wk + q * 256;
    #pragma unroll
    for (int k = 0; k < 4; ++k) {
        const int nn = nb + 8 * k;
        float sq_ = bqv, sk_ = bkv;
        for (int c = 0; c < 256; ++c) {
            const float yv = ys[c][nn];
            sq_ += wqp[c] * yv;
            sk_ += wkp[c] * yv;
        }
        Q[(size_t)((b << 10) + n0 + nn) * 32 + q] = sq_;
        K[(size_t)((b << 5) + q) * 1024 + n0 + nn] = sk_;
    }
    const int nn2 = tid & 31;
    for (int k = 0; k < 32; ++k) {
        const int v = (tid >> 5) + 8 * k;
        float s = bv[v];
        const float* wvp = wv + v * 256;
        for (int c = 0; c < 256; ++c) s += wvp[c] * ys[c][nn2];
        V[(size_t)((b << 8) + v) * 1024 + n0 + nn2] = f2b(s);
    }
}

__global__ __launch_bounds__(256) void attn_k(
    const float* __restrict__ Q, const float* __restrict__ K, bf16* __restrict__ attn)
{
    const int b = blockIdx.x >> 10;
    const int n = blockIdx.x & 1023;
    __shared__ float qs[32];
    __shared__ float red[256];
    const int tid = threadIdx.x;
    if (tid < 32) qs[tid] = Q[(size_t)((b << 10) + n) * 32 + tid];
    __syncthreads();
    float s[4];
    #pragma unroll
    for (int k = 0; k < 4; ++k) {
        const int m = tid + (k << 8);
        float acc = 0.f;
        #pragma unroll
        for (int q = 0; q < 32; ++q) acc += qs[q] * K[(size_t)((b << 5) + q) * 1024 + m];
        s[k] = acc;
    }
    float mx = fmaxf(fmaxf(s[0], s[1]), fmaxf(s[2], s[3]));
    red[tid] = mx; __syncthreads();
    for (int o = 128; o > 0; o >>= 1) {
        if (tid < o) red[tid] = fmaxf(red[tid], red[tid + o]);
        __syncthreads();
    }
    mx = red[0]; __syncthreads();
    float sum = 0.f;
    #pragma unroll
    for (int k = 0; k < 4; ++k) { s[k] = expf(s[k] - mx); sum += s[k]; }
    red[tid] = sum; __syncthreads();
    for (int o = 128; o > 0; o >>= 1) {
        if (tid < o) red[tid] += red[tid + o];
        __syncthreads();
    }
    const float inv = 1.f / red[0];
    #pragma unroll
    for (int k = 0; k < 4; ++k)
        attn[(size_t)((b << 10) + n) * 1024 + tid + (k << 8)] = f2b(s[k] * inv);
}

__global__ __launch_bounds__(256) void pv_k(
    const bf16* __restrict__ V, const bf16* __restrict__ attn,
    const bf16* __restrict__ y, const float* __restrict__ gamma, float* __restrict__ out)
{
    const int blk = blockIdx.x;
    const int b  = blk >> 6;
    const int c0 = ((blk >> 4) & 3) * 64;
    const int n0 = (blk & 15) * 64;
    __shared__ float Vt[64][33], At[64][33];
    const int tid = threadIdx.x;
    const int tc = tid >> 4, tn = tid & 15;
    float acc[4][4] = {{0.f}};
    for (int m0 = 0; m0 < 1024; m0 += 32) {
        const int r = tid >> 2, cs = (tid & 3) * 8;
        const bf16* vp = V    + (size_t)((b << 8) + c0 + r) * 1024 + m0 + cs;
        const bf16* ap = attn + (size_t)((b << 10) + n0 + r) * 1024 + m0 + cs;
        #pragma unroll
        for (int j = 0; j < 8; ++j) Vt[r][cs + j] = b2f(vp[j]);
        #pragma unroll
        for (int j = 0; j < 8; ++j) At[r][cs + j] = b2f(ap[j]);
        __syncthreads();
        for (int mm = 0; mm < 32; ++mm) {
            float vv[4], aa[4];
            #pragma unroll
            for (int i = 0; i < 4; ++i) vv[i] = Vt[tc * 4 + i][mm];
            #pragma unroll
            for (int j = 0; j < 4; ++j) aa[j] = At[tn * 4 + j][mm];
            #pragma unroll
            for (int i = 0; i < 4; ++i)
                #pragma unroll
                for (int j = 0; j < 4; ++j) acc[i][j] += vv[i] * aa[j];
        }
        __syncthreads();
    }
    const float g = gamma[0];
    #pragma unroll
    for (int i = 0; i < 4; ++i) {
        const int c = c0 + tc * 4 + i;
        #pragma unroll
        for (int j = 0; j < 4; ++j) {
            const int n = n0 + tn * 4 + j;
            const size_t idx = (size_t)((b << 8) + c) * 1024 + n;
            out[idx] = g * acc[i][j] + b2f(y[idx]);
        }
    }
}

// ---------------------------------------------------------------------------
// Workspace (~53.5 MB):
//  ws+0      te 16KB | ws+16K sums 2KB | ws+18K scale 1KB | ws+19K shift 1KB
//  base = ws+32K:
//   W3_1 [0,1.125M) W3_2 [1.125,2.25) W3_3 [2.25,3.375)
//   Xp0 [3538944, +9469952)  Xp1 [13008896, +9469952)
//   Craw [22478848, +8388608)  Yt [30867456, +8388608)
//   Q [0,2M) K [2M,4M) attn [4M,36M)   (alias dead W3/Xp/Craw/Yt)
//   Y [39256064, +8M)  V [47644672, +8M)
// ---------------------------------------------------------------------------
extern "C" void kernel_launch(void* const* d_in, const int* in_sizes, int n_in,
                              void* d_out, int out_size, void* d_ws, size_t ws_size,
                              hipStream_t stream)
{
    const float* x     = (const float*)d_in[0];
    const float* t     = (const float*)d_in[1];
    const float* w_t1  = (const float*)d_in[2];
    const float* b_t1  = (const float*)d_in[3];
    const float* w_t2  = (const float*)d_in[4];
    const float* b_t2  = (const float*)d_in[5];
    const float* w_c1  = (const float*)d_in[6];
    const float* b_c1  = (const float*)d_in[7];
    const float* w_c2  = (const float*)d_in[8];
    const float* b_c2  = (const float*)d_in[9];
    const float* w_tr  = (const float*)d_in[10];
    const float* b_tr  = (const float*)d_in[11];
    const float* bn1g  = (const float*)d_in[12];
    const float* bn1b  = (const float*)d_in[13];
    const float* bn2g  = (const float*)d_in[14];
    const float* bn2b  = (const float*)d_in[15];
    const float* wq    = (const float*)d_in[16];
    const float* bq    = (const float*)d_in[17];
    const float* wk    = (const float*)d_in[18];
    const float* bk    = (const float*)d_in[19];
    const float* wv    = (const float*)d_in[20];
    const float* bv    = (const float*)d_in[21];
    const float* gamma = (const float*)d_in[22];
    float* out = (float*)d_out;

    char* ws = (char*)d_ws;
    float* te    = (float*)(ws + 0);
    float* sums  = (float*)(ws + 16384);
    float* scale = (float*)(ws + 18432);
    float* shift = (float*)(ws + 19456);
    char* base = ws + 32768;
    bf16* W3_1 = (bf16*)(base);
    bf16* W3_2 = (bf16*)(base + 1179648);
    bf16* W3_3 = (bf16*)(base + 2359296);
    bf16* Xp0  = (bf16*)(base + 3538944);
    bf16* Xp1  = (bf16*)(base + 13008896);
    bf16* Craw = (bf16*)(base + 22478848);
    bf16* Yt   = (bf16*)(base + 30867456);
    float* Q   = (float*)(base);                 // alias (dead W3_1/2)
    float* K   = (float*)(base + 2097152);       // alias (dead W3_3/Xp0 head)
    bf16*  attn= (bf16*)(base + 4194304);        // alias (dead Xp/Craw/Yt head)
    bf16*  Y   = (bf16*)(base + 39256064);
    bf16*  V   = (bf16*)(base + 47644672);

    const unsigned int XP_U32 = 16u * 1156u * 256u / 2u;   // 2367488

    zero_k<<<2048, 256, 0, stream>>>((unsigned int*)Xp0, XP_U32);
    zero_k<<<2048, 256, 0, stream>>>((unsigned int*)Xp1, XP_U32);
    zero_k<<<2, 256, 0, stream>>>((unsigned int*)sums, 512);
    time_mlp_k<<<16, 256, 0, stream>>>(t, w_t1, b_t1, w_t2, b_t2, te);
    prep_w_k<<<2304, 256, 0, stream>>>(w_c1, W3_1);
    prep_w_k<<<2304, 256, 0, stream>>>(w_c2, W3_2);
    prep_w_k<<<2304, 256, 0, stream>>>(w_tr, W3_3);
    prep_x_k<<<1024, 256, 0, stream>>>(x, Xp0);

    conv_mfma_k<true><<<256, 256, 0, stream>>>(Xp0, W3_1, b_c1, Craw);
    bn_stats_T_k<<<256, 256, 0, stream>>>(Craw, sums);
    bn_fin_k<<<1, 256, 0, stream>>>(sums, bn1g, bn1b, scale, shift);
    bn_apply_T_k<true><<<2048, 256, 0, stream>>>(Craw, scale, shift, te, Xp1);

    zero_k<<<2, 256, 0, stream>>>((unsigned int*)sums, 512);
    conv_mfma_k<true><<<256, 256, 0, stream>>>(Xp1, W3_2, b_c2, Craw);
    bn_stats_T_k<<<256, 256, 0, stream>>>(Craw, sums);
    bn_fin_k<<<1, 256, 0, stream>>>(sums, bn2g, bn2b, scale, shift);
    bn_apply_T_k<false><<<2048, 256, 0, stream>>>(Craw, scale, shift, nullptr, Xp0);

    conv_mfma_k<false><<<256, 256, 0, stream>>>(Xp0, W3_3, b_tr, Yt);
    transpose_Y_k<<<1024, 256, 0, stream>>>(Yt, Y);

    qkv_k<<<512, 256, 0, stream>>>(Y, wq, bq, wk, bk, wv, bv, Q, K, V);
    attn_k<<<16384, 256, 0, stream>>>(Q, K, attn);
    pv_k<<<1024, 256, 0, stream>>>(V, attn, Y, gamma, out);
}

// Round 5
// 266.221 us; speedup vs baseline: 16.2754x; 2.6959x over previous
//
#include <hip/hip_runtime.h>
#include <hip/hip_bf16.h>

using bf16 = __hip_bfloat16;

typedef __attribute__((ext_vector_type(8))) short bf16x8_t;
typedef __attribute__((ext_vector_type(4))) float f32x4_t;

__device__ __forceinline__ float b2f(bf16 x){ return __bfloat162float(x); }
__device__ __forceinline__ bf16  f2b(float x){ return __float2bfloat16(x); }
__device__ __forceinline__ unsigned short f2bu(float x){ bf16 h = __float2bfloat16(x); return *(unsigned short*)&h; }
__device__ __forceinline__ float bits2f(unsigned int lo16){ return __uint_as_float(lo16 << 16); }

__device__ __forceinline__ void gload16(const void* g, void* l) {
    __builtin_amdgcn_global_load_lds(
        (const __attribute__((address_space(1))) unsigned int*)g,
        (__attribute__((address_space(3))) unsigned int*)l, 16, 0, 0);
}

// ---------------------------------------------------------------------------
// Dims: B=16, C=256, H=W=32, N=1024, padded P=34x34=1156, Cq=32
// ---------------------------------------------------------------------------

__global__ void zero_k(unsigned int* __restrict__ p, unsigned int n) {
    for (unsigned int i = blockIdx.x * 256 + threadIdx.x; i < n; i += gridDim.x * 256) p[i] = 0u;
}

__global__ __launch_bounds__(256) void time_mlp_k(
    const float* __restrict__ t, const float* __restrict__ w1, const float* __restrict__ b1,
    const float* __restrict__ w2, const float* __restrict__ b2, float* __restrict__ te)
{
    const int b = blockIdx.x, j = threadIdx.x;
    __shared__ float tr[256], hid[256];
    tr[j] = t[(b << 8) + j];
    __syncthreads();
    float s = b1[j];
    const float* wp = w1 + j * 256;
    for (int k = 0; k < 256; ++k) s += tr[k] * wp[k];
    hid[j] = fmaxf(s, 0.f);
    __syncthreads();
    float s2 = b2[j];
    const float* wp2 = w2 + j * 256;
    for (int k = 0; k < 256; ++k) s2 += hid[k] * wp2[k];
    te[(b << 8) + j] = fmaxf(s2, 0.f);
}

// weights [co][ci][3][3] fp32 -> W3 [co][off][ci] bf16
__global__ __launch_bounds__(256) void prep_w_k(const float* __restrict__ w, bf16* __restrict__ W3)
{
    const int blk = blockIdx.x;            // co*9 + off
    const int ci = threadIdx.x;
    const int co = blk / 9, off = blk % 9;
    W3[(size_t)blk * 256 + ci] = f2b(w[(size_t)co * 2304 + ci * 9 + off]);
}

// wq[32][256], wk[32][256] -> WQK[64][256] bf16
__global__ __launch_bounds__(256) void prep_wqk_k(
    const float* __restrict__ wq, const float* __restrict__ wk, bf16* __restrict__ WQK)
{
    const int r = blockIdx.x, c = threadIdx.x;
    const float v = (r < 32) ? wq[r * 256 + c] : wk[(r - 32) * 256 + c];
    WQK[r * 256 + c] = f2b(v);
}

// wv[256][256] fp32 -> bf16
__global__ __launch_bounds__(256) void prep_wv_k(const float* __restrict__ wv, bf16* __restrict__ WVb)
{
    const int r = blockIdx.x, c = threadIdx.x;
    WVb[r * 256 + c] = f2b(wv[r * 256 + c]);
}

// x fp32 [b][c][n] -> Xp bf16 [b][1156][c] (interior only; halo pre-zeroed)
__global__ __launch_bounds__(256) void prep_x_k(const float* __restrict__ x, bf16* __restrict__ Xp)
{
    __shared__ float xs[64][65];
    const int t = threadIdx.x;
    const int b = blockIdx.x >> 6, ct = (blockIdx.x >> 4) & 3, nt = blockIdx.x & 15;
    const int c0 = ct << 6, n0 = nt << 6;
    {
        const int cl = t >> 2, nc = (t & 3) << 4;
        const float* src = x + (size_t)((b << 8) + c0 + cl) * 1024 + n0 + nc;
        #pragma unroll
        for (int j = 0; j < 16; j += 4) {
            const float4 v = *(const float4*)(src + j);
            xs[cl][nc + j] = v.x; xs[cl][nc + j + 1] = v.y;
            xs[cl][nc + j + 2] = v.z; xs[cl][nc + j + 3] = v.w;
        }
    }
    __syncthreads();
    {
        const int nl = t >> 2, cc = (t & 3) << 4;
        const int n = n0 + nl;
        const int p = ((n >> 5) + 1) * 34 + (n & 31) + 1;
        unsigned int u[8];
        #pragma unroll
        for (int k = 0; k < 8; ++k)
            u[k] = (unsigned int)f2bu(xs[cc + 2 * k][nl]) | ((unsigned int)f2bu(xs[cc + 2 * k + 1][nl]) << 16);
        bf16* dst = Xp + (size_t)(b * 1156 + p) * 256 + c0 + cc;
        *(uint4*)dst = make_uint4(u[0], u[1], u[2], u[3]);
        *(uint4*)(dst + 8) = make_uint4(u[4], u[5], u[6], u[7]);
    }
}

// conv3x3 as implicit GEMM via MFMA (unchanged from round 4).
template<bool RELU>
__global__ __launch_bounds__(256, 1) void conv_mfma_k(
    const bf16* __restrict__ Xp, const bf16* __restrict__ W3,
    const float* __restrict__ bias, bf16* __restrict__ outp)
{
    __shared__ bf16 Als[128 * 64];
    __shared__ bf16 Bls[128 * 64];
    const int tid = threadIdx.x;
    const int wid = tid >> 6, lane = tid & 63;
    const int wm = wid >> 1, wn = wid & 1;
    const int blk = blockIdx.x;
    const int b = blk >> 4, mt = (blk >> 1) & 7, nt = blk & 1;
    const int m0 = mt << 7, co0 = nt << 7;

    const int srow = (wid << 5) + (lane >> 3);
    const int sL8 = (((lane & 7) ^ (lane >> 3)) << 3);

    const bf16* agp[4]; const bf16* bgp[4];
    bf16* aldst[4]; bf16* bldst[4];
    #pragma unroll
    for (int i = 0; i < 4; ++i) {
        const int r = srow + i * 8;
        const int n = m0 + r;
        const int pb = (n >> 5) * 34 + (n & 31);
        agp[i] = Xp + (size_t)(b * 1156 + pb) * 256 + sL8;
        bgp[i] = W3 + (size_t)(co0 + r) * 2304 + sL8;
        aldst[i] = Als + ((wid << 5) + i * 8) * 64;
        bldst[i] = Bls + ((wid << 5) + i * 8) * 64;
    }

    const int rsel = lane & 15;
    const int s0 = (((lane >> 4) ^ (lane & 7)) << 3);
    const int s1 = ((((lane >> 4) + 4) ^ (lane & 7)) << 3);
    const int arow = ((wm << 6) + rsel) << 6;
    const int brow = ((wn << 6) + rsel) << 6;

    f32x4_t acc[4][4];
    #pragma unroll
    for (int mi = 0; mi < 4; ++mi)
        #pragma unroll
        for (int ni = 0; ni < 4; ++ni)
            acc[mi][ni] = (f32x4_t){0.f, 0.f, 0.f, 0.f};

    int kt = 0;
    for (int off = 0; off < 9; ++off) {
        const int kh3 = (off * 11) >> 5;
        const int doff = (off + 31 * kh3) << 8;
        const int koff0 = off << 8;
        for (int cic = 0; cic < 4; ++cic, ++kt) {
            if (kt) __syncthreads();
            const int k64 = cic << 6;
            #pragma unroll
            for (int i = 0; i < 4; ++i) {
                gload16(agp[i] + doff + k64, aldst[i]);
                gload16(bgp[i] + koff0 + k64, bldst[i]);
            }
            __syncthreads();
            #pragma unroll
            for (int kh = 0; kh < 2; ++kh) {
                const int sk = kh ? s1 : s0;
                bf16x8_t av[4], bv[4];
                #pragma unroll
                for (int mi = 0; mi < 4; ++mi)
                    av[mi] = *(const bf16x8_t*)(Als + arow + (mi << 10) + sk);
                #pragma unroll
                for (int ni = 0; ni < 4; ++ni)
                    bv[ni] = *(const bf16x8_t*)(Bls + brow + (ni << 10) + sk);
                #pragma unroll
                for (int mi = 0; mi < 4; ++mi)
                    #pragma unroll
                    for (int ni = 0; ni < 4; ++ni)
                        acc[mi][ni] = __builtin_amdgcn_mfma_f32_16x16x32_bf16(
                            av[mi], bv[ni], acc[mi][ni], 0, 0, 0);
            }
        }
    }

    const int cr = (lane >> 4) << 2;
    const int cc = lane & 15;
    #pragma unroll
    for (int ni = 0; ni < 4; ++ni) {
        const int co = co0 + (wn << 6) + (ni << 4) + cc;
        const float bb = bias[co];
        #pragma unroll
        for (int mi = 0; mi < 4; ++mi) {
            const int n = m0 + (wm << 6) + (mi << 4) + cr;
            #pragma unroll
            for (int j = 0; j < 4; ++j) {
                float v = acc[mi][ni][j] + bb;
                if (RELU) v = fmaxf(v, 0.f);
                outp[(size_t)((b << 10) + n + j) * 256 + co] = f2b(v);
            }
        }
    }
}

// bn stats over pixel-major Craw [16384][256]
__global__ __launch_bounds__(256) void bn_stats_T_k(
    const bf16* __restrict__ a, float* __restrict__ sums)
{
    __shared__ float ls[256], lq[256];
    const int t = threadIdx.x;
    ls[t] = 0.f; lq[t] = 0.f;
    __syncthreads();
    const int g = t >> 5, c0 = (t & 31) << 3;
    float s[8] = {0,0,0,0,0,0,0,0}, q[8] = {0,0,0,0,0,0,0,0};
    const int rbase = blockIdx.x * 64;
    for (int rr = g; rr < 64; rr += 8) {
        const uint4 u = *(const uint4*)(a + (size_t)(rbase + rr) * 256 + c0);
        const unsigned int w[4] = {u.x, u.y, u.z, u.w};
        #pragma unroll
        for (int k = 0; k < 4; ++k) {
            const float v0 = bits2f(w[k] & 0xffffu);
            const float v1 = __uint_as_float(w[k] & 0xffff0000u);
            s[2 * k] += v0; q[2 * k] += v0 * v0;
            s[2 * k + 1] += v1; q[2 * k + 1] += v1 * v1;
        }
    }
    #pragma unroll
    for (int j = 0; j < 8; ++j) {
        atomicAdd(&ls[c0 + j], s[j]);
        atomicAdd(&lq[c0 + j], q[j]);
    }
    __syncthreads();
    atomicAdd(&sums[t], ls[t]);
    atomicAdd(&sums[256 + t], lq[t]);
}

__global__ __launch_bounds__(256) void bn_fin_k(
    const float* __restrict__ sums, const float* __restrict__ g, const float* __restrict__ bb,
    float* __restrict__ scale, float* __restrict__ shift)
{
    const int c = threadIdx.x;
    const float m = sums[c] * (1.f / 16384.f);
    const float var = sums[256 + c] * (1.f / 16384.f) - m * m;
    const float sc = g[c] * rsqrtf(var + 1e-5f);
    scale[c] = sc; shift[c] = bb[c] - m * sc;
}

template<bool TE>
__global__ __launch_bounds__(256) void bn_apply_T_k(
    const bf16* __restrict__ a, const float* __restrict__ scale,
    const float* __restrict__ shift, const float* __restrict__ te,
    bf16* __restrict__ Xp)
{
    const int t = threadIdx.x;
    const int row = blockIdx.x * 8 + (t >> 5);
    const int c0 = (t & 31) << 3;
    const int b = row >> 10, n = row & 1023;
    const uint4 u = *(const uint4*)(a + (size_t)row * 256 + c0);
    const unsigned int w[4] = {u.x, u.y, u.z, u.w};
    const float4 sc0 = *(const float4*)(scale + c0);
    const float4 sc1 = *(const float4*)(scale + c0 + 4);
    const float4 sh0 = *(const float4*)(shift + c0);
    const float4 sh1 = *(const float4*)(shift + c0 + 4);
    const float scv[8] = {sc0.x, sc0.y, sc0.z, sc0.w, sc1.x, sc1.y, sc1.z, sc1.w};
    const float shv[8] = {sh0.x, sh0.y, sh0.z, sh0.w, sh1.x, sh1.y, sh1.z, sh1.w};
    float tev[8] = {0,0,0,0,0,0,0,0};
    if (TE) {
        const float4 t0 = *(const float4*)(te + (b << 8) + c0);
        const float4 t1 = *(const float4*)(te + (b << 8) + c0 + 4);
        tev[0]=t0.x; tev[1]=t0.y; tev[2]=t0.z; tev[3]=t0.w;
        tev[4]=t1.x; tev[5]=t1.y; tev[6]=t1.z; tev[7]=t1.w;
    }
    unsigned int o[4];
    #pragma unroll
    for (int k = 0; k < 4; ++k) {
        const float v0 = bits2f(w[k] & 0xffffu) * scv[2*k] + shv[2*k] + tev[2*k];
        const float v1 = __uint_as_float(w[k] & 0xffff0000u) * scv[2*k+1] + shv[2*k+1] + tev[2*k+1];
        o[k] = (unsigned int)f2bu(v0) | ((unsigned int)f2bu(v1) << 16);
    }
    const int p = ((n >> 5) + 1) * 34 + (n & 31) + 1;
    *(uint4*)(Xp + (size_t)(b * 1156 + p) * 256 + c0) = make_uint4(o[0], o[1], o[2], o[3]);
}

// Q|K projection: QKb[b][n][64] = Yt[n][c] @ WQK[q][c]^T + (bq|bk)
__global__ __launch_bounds__(256) void qk_mfma_k(
    const bf16* __restrict__ Yt, const bf16* __restrict__ WQK,
    const float* __restrict__ bq, const float* __restrict__ bk, bf16* __restrict__ QKb)
{
    const int b = blockIdx.x >> 4, m0 = (blockIdx.x & 15) << 6;
    const int tid = threadIdx.x, wid = tid >> 6, lane = tid & 63;
    const int n0w = m0 + (wid << 4);
    const bf16* arow = Yt + (size_t)((b << 10) + n0w + (lane & 15)) * 256 + ((lane >> 4) << 3);
    const int boff = ((lane >> 4) << 3);
    f32x4_t acc[4];
    #pragma unroll
    for (int ni = 0; ni < 4; ++ni) acc[ni] = (f32x4_t){0.f,0.f,0.f,0.f};
    for (int k0 = 0; k0 < 256; k0 += 32) {
        const bf16x8_t av = *(const bf16x8_t*)(arow + k0);
        #pragma unroll
        for (int ni = 0; ni < 4; ++ni) {
            const bf16x8_t bv = *(const bf16x8_t*)(WQK + (ni * 16 + (lane & 15)) * 256 + k0 + boff);
            acc[ni] = __builtin_amdgcn_mfma_f32_16x16x32_bf16(av, bv, acc[ni], 0, 0, 0);
        }
    }
    const int cr = (lane >> 4) << 2, cc = lane & 15;
    #pragma unroll
    for (int ni = 0; ni < 4; ++ni) {
        const int q = ni * 16 + cc;
        const float bias = (q < 32) ? bq[q] : bk[q - 32];
        #pragma unroll
        for (int j = 0; j < 4; ++j) {
            const int n = n0w + cr + j;
            QKb[(size_t)((b << 10) + n) * 64 + q] = f2b(acc[ni][j] + bias);
        }
    }
}

// V projection: Vb[b][v][n] = WV[v][c] @ Yt[n][c]^T + bv   (128x128 tile, LDS staged)
__global__ __launch_bounds__(256, 1) void v_mfma_k(
    const bf16* __restrict__ WVb, const bf16* __restrict__ Yt,
    const float* __restrict__ bvp, bf16* __restrict__ Vb)
{
    __shared__ bf16 Als[128 * 64];
    __shared__ bf16 Bls[128 * 64];
    const int tid = threadIdx.x;
    const int wid = tid >> 6, lane = tid & 63;
    const int wm = wid >> 1, wn = wid & 1;
    const int blk = blockIdx.x;
    const int b = blk >> 4, vt = (blk >> 3) & 1, nt = blk & 7;
    const int v0 = vt << 7, n0 = nt << 7;

    const int srow = (wid << 5) + (lane >> 3);
    const int sL8 = (((lane & 7) ^ (lane >> 3)) << 3);
    const bf16* agp[4]; const bf16* bgp[4];
    bf16* aldst[4]; bf16* bldst[4];
    #pragma unroll
    for (int i = 0; i < 4; ++i) {
        const int r = srow + i * 8;
        agp[i] = WVb + (size_t)(v0 + r) * 256 + sL8;
        bgp[i] = Yt + (size_t)((b << 10) + n0 + r) * 256 + sL8;
        aldst[i] = Als + ((wid << 5) + i * 8) * 64;
        bldst[i] = Bls + ((wid << 5) + i * 8) * 64;
    }
    const int rsel = lane & 15;
    const int s0 = (((lane >> 4) ^ (lane & 7)) << 3);
    const int s1 = ((((lane >> 4) + 4) ^ (lane & 7)) << 3);
    const int arow = ((wm << 6) + rsel) << 6;
    const int brow = ((wn << 6) + rsel) << 6;

    f32x4_t acc[4][4];
    #pragma unroll
    for (int mi = 0; mi < 4; ++mi)
        #pragma unroll
        for (int ni = 0; ni < 4; ++ni)
            acc[mi][ni] = (f32x4_t){0.f,0.f,0.f,0.f};

    for (int kt = 0; kt < 4; ++kt) {
        if (kt) __syncthreads();
        const int k64 = kt << 6;
        #pragma unroll
        for (int i = 0; i < 4; ++i) {
            gload16(agp[i] + k64, aldst[i]);
            gload16(bgp[i] + k64, bldst[i]);
        }
        __syncthreads();
        #pragma unroll
        for (int kh = 0; kh < 2; ++kh) {
            const int sk = kh ? s1 : s0;
            bf16x8_t av[4], bv[4];
            #pragma unroll
            for (int mi = 0; mi < 4; ++mi)
                av[mi] = *(const bf16x8_t*)(Als + arow + (mi << 10) + sk);
            #pragma unroll
            for (int ni = 0; ni < 4; ++ni)
                bv[ni] = *(const bf16x8_t*)(Bls + brow + (ni << 10) + sk);
            #pragma unroll
            for (int mi = 0; mi < 4; ++mi)
                #pragma unroll
                for (int ni = 0; ni < 4; ++ni)
                    acc[mi][ni] = __builtin_amdgcn_mfma_f32_16x16x32_bf16(
                        av[mi], bv[ni], acc[mi][ni], 0, 0, 0);
        }
    }

    const int cr = (lane >> 4) << 2, cc = lane & 15;
    #pragma unroll
    for (int mi = 0; mi < 4; ++mi) {
        #pragma unroll
        for (int j = 0; j < 4; ++j) {
            const int v = v0 + (wm << 6) + (mi << 4) + cr + j;
            const float bb = bvp[v];
            #pragma unroll
            for (int ni = 0; ni < 4; ++ni) {
                const int n = n0 + (wn << 6) + (ni << 4) + cc;
                Vb[(size_t)((b << 8) + v) * 1024 + n] = f2b(acc[mi][ni][j] + bb);
            }
        }
    }
}

// scores + softmax (unnormalized): P[b][n][m] = exp(S - rowmax), invs[b][n] = 1/rowsum
// computes S^T via mfma(K_rows, Q_rows) so the m-reduction is lane-local.
__global__ __launch_bounds__(256) void softmax_k(
    const bf16* __restrict__ QKb, bf16* __restrict__ P, float* __restrict__ invs)
{
    const int b = blockIdx.x >> 5, n0 = (blockIdx.x & 31) << 5;
    const int tid = threadIdx.x, wid = tid >> 6, lane = tid & 63;
    const int m0w = wid << 8;
    __shared__ float wred[4][32];

    const bf16* qbase = QKb + (size_t)((b << 10) + n0) * 64;
    const int koff = (lane >> 4) << 3;
    bf16x8_t qf[2];
    #pragma unroll
    for (int nt = 0; nt < 2; ++nt)
        qf[nt] = *(const bf16x8_t*)(qbase + (nt * 16 + (lane & 15)) * 64 + koff);
    const bf16* kbase = QKb + (size_t)(b << 10) * 64 + 32;

    // pass 1: row max
    float mx[2] = {-3.0e38f, -3.0e38f};
    for (int mi = 0; mi < 16; ++mi) {
        const bf16x8_t kf = *(const bf16x8_t*)(kbase + (m0w + mi * 16 + (lane & 15)) * 64 + koff);
        #pragma unroll
        for (int nt = 0; nt < 2; ++nt) {
            f32x4_t s = (f32x4_t){0.f,0.f,0.f,0.f};
            s = __builtin_amdgcn_mfma_f32_16x16x32_bf16(kf, qf[nt], s, 0, 0, 0);
            mx[nt] = fmaxf(mx[nt], fmaxf(fmaxf(s[0], s[1]), fmaxf(s[2], s[3])));
        }
    }
    #pragma unroll
    for (int nt = 0; nt < 2; ++nt) {
        mx[nt] = fmaxf(mx[nt], __shfl_xor(mx[nt], 16));
        mx[nt] = fmaxf(mx[nt], __shfl_xor(mx[nt], 32));
        if (lane < 16) wred[wid][nt * 16 + lane] = mx[nt];
    }
    __syncthreads();
    float rm[2];
    #pragma unroll
    for (int nt = 0; nt < 2; ++nt) {
        const int c = nt * 16 + (lane & 15);
        rm[nt] = fmaxf(fmaxf(wred[0][c], wred[1][c]), fmaxf(wred[2][c], wred[3][c]));
    }
    __syncthreads();

    // pass 2: exp, sum, write
    float sm[2] = {0.f, 0.f};
    for (int mi = 0; mi < 16; ++mi) {
        const bf16x8_t kf = *(const bf16x8_t*)(kbase + (m0w + mi * 16 + (lane & 15)) * 64 + koff);
        #pragma unroll
        for (int nt = 0; nt < 2; ++nt) {
            f32x4_t s = (f32x4_t){0.f,0.f,0.f,0.f};
            s = __builtin_amdgcn_mfma_f32_16x16x32_bf16(kf, qf[nt], s, 0, 0, 0);
            const float p0 = __expf(s[0] - rm[nt]);
            const float p1 = __expf(s[1] - rm[nt]);
            const float p2 = __expf(s[2] - rm[nt]);
            const float p3 = __expf(s[3] - rm[nt]);
            sm[nt] += (p0 + p1) + (p2 + p3);
            uint2 u;
            u.x = (unsigned int)f2bu(p0) | ((unsigned int)f2bu(p1) << 16);
            u.y = (unsigned int)f2bu(p2) | ((unsigned int)f2bu(p3) << 16);
            const int n = n0 + nt * 16 + (lane & 15);
            const int m = m0w + mi * 16 + ((lane >> 4) << 2);
            *(uint2*)(P + (size_t)((b << 10) + n) * 1024 + m) = u;
        }
    }
    #pragma unroll
    for (int nt = 0; nt < 2; ++nt) {
        sm[nt] += __shfl_xor(sm[nt], 16);
        sm[nt] += __shfl_xor(sm[nt], 32);
        if (lane < 16) wred[wid][nt * 16 + lane] = sm[nt];
    }
    __syncthreads();
    if (tid < 32) {
        const float total = wred[0][tid] + wred[1][tid] + wred[2][tid] + wred[3][tid];
        invs[(b << 10) + n0 + tid] = 1.f / total;
    }
}

// PV + residual: out[b][c][n] = gamma*invs[n]*(Vb[c][:] . P[n][:]) + Yt[n][c]
__global__ __launch_bounds__(256, 1) void pv_mfma_k(
    const bf16* __restrict__ Vb, const bf16* __restrict__ P,
    const float* __restrict__ invs, const bf16* __restrict__ Yt,
    const float* __restrict__ gamma, float* __restrict__ out)
{
    __shared__ bf16 Als[128 * 64];
    __shared__ bf16 Bls[128 * 64];
    const int tid = threadIdx.x;
    const int wid = tid >> 6, lane = tid & 63;
    const int wm = wid >> 1, wn = wid & 1;
    const int blk = blockIdx.x;
    const int b = blk >> 4, ct = (blk >> 3) & 1, nt = blk & 7;
    const int c0 = ct << 7, n0 = nt << 7;

    const int srow = (wid << 5) + (lane >> 3);
    const int sL8 = (((lane & 7) ^ (lane >> 3)) << 3);
    const bf16* agp[4]; const bf16* bgp[4];
    bf16* aldst[4]; bf16* bldst[4];
    #pragma unroll
    for (int i = 0; i < 4; ++i) {
        const int r = srow + i * 8;
        agp[i] = Vb + (size_t)((b << 8) + c0 + r) * 1024 + sL8;
        bgp[i] = P + (size_t)((b << 10) + n0 + r) * 1024 + sL8;
        aldst[i] = Als + ((wid << 5) + i * 8) * 64;
        bldst[i] = Bls + ((wid << 5) + i * 8) * 64;
    }
    const int rsel = lane & 15;
    const int s0 = (((lane >> 4) ^ (lane & 7)) << 3);
    const int s1 = ((((lane >> 4) + 4) ^ (lane & 7)) << 3);
    const int arow = ((wm << 6) + rsel) << 6;
    const int brow = ((wn << 6) + rsel) << 6;

    f32x4_t acc[4][4];
    #pragma unroll
    for (int mi = 0; mi < 4; ++mi)
        #pragma unroll
        for (int ni = 0; ni < 4; ++ni)
            acc[mi][ni] = (f32x4_t){0.f,0.f,0.f,0.f};

    for (int kt = 0; kt < 16; ++kt) {
        if (kt) __syncthreads();
        const int k64 = kt << 6;
        #pragma unroll
        for (int i = 0; i < 4; ++i) {
            gload16(agp[i] + k64, aldst[i]);
            gload16(bgp[i] + k64, bldst[i]);
        }
        __syncthreads();
        #pragma unroll
        for (int kh = 0; kh < 2; ++kh) {
            const int sk = kh ? s1 : s0;
            bf16x8_t av[4], bv[4];
            #pragma unroll
            for (int mi = 0; mi < 4; ++mi)
                av[mi] = *(const bf16x8_t*)(Als + arow + (mi << 10) + sk);
            #pragma unroll
            for (int ni = 0; ni < 4; ++ni)
                bv[ni] = *(const bf16x8_t*)(Bls + brow + (ni << 10) + sk);
            #pragma unroll
            for (int mi = 0; mi < 4; ++mi)
                #pragma unroll
                for (int ni = 0; ni < 4; ++ni)
                    acc[mi][ni] = __builtin_amdgcn_mfma_f32_16x16x32_bf16(
                        av[mi], bv[ni], acc[mi][ni], 0, 0, 0);
        }
    }

    const float g = gamma[0];
    const int cr = (lane >> 4) << 2, cc = lane & 15;
    #pragma unroll
    for (int ni = 0; ni < 4; ++ni) {
        const int n = n0 + (wn << 6) + (ni << 4) + cc;
        const float gi = g * invs[(b << 10) + n];
        #pragma unroll
        for (int mi = 0; mi < 4; ++mi) {
            const int c = c0 + (wm << 6) + (mi << 4) + cr;
            const bf16* yp = Yt + (size_t)((b << 10) + n) * 256 + c;
            #pragma unroll
            for (int j = 0; j < 4; ++j)
                out[(size_t)((b << 8) + c + j) * 1024 + n] = gi * acc[mi][ni][j] + b2f(yp[j]);
        }
    }
}

// ---------------------------------------------------------------------------
// Workspace (base = ws+32K; ~52.7 MB):
//  W3_1 [0) W3_2 [1179648) W3_3 [2359296)
//  Xp0 [3538944, +9469952) Xp1 [13008896, +9469952) Craw [22478848, +8388608)
//  P [0, 33554432)  -- aliases W3/Xp/Craw (all dead before softmax)
//  Yt [33554432, +8388608) QKb [41943040, +2097152) Vb [44040192, +8388608)
//  invs [52428800, +65536) WQK [52494336, +32768) WVb [52527104, +131072)
// ---------------------------------------------------------------------------
extern "C" void kernel_launch(void* const* d_in, const int* in_sizes, int n_in,
                              void* d_out, int out_size, void* d_ws, size_t ws_size,
                              hipStream_t stream)
{
    const float* x     = (const float*)d_in[0];
    const float* t     = (const float*)d_in[1];
    const float* w_t1  = (const float*)d_in[2];
    const float* b_t1  = (const float*)d_in[3];
    const float* w_t2  = (const float*)d_in[4];
    const float* b_t2  = (const float*)d_in[5];
    const float* w_c1  = (const float*)d_in[6];
    const float* b_c1  = (const float*)d_in[7];
    const float* w_c2  = (const float*)d_in[8];
    const float* b_c2  = (const float*)d_in[9];
    const float* w_tr  = (const float*)d_in[10];
    const float* b_tr  = (const float*)d_in[11];
    const float* bn1g  = (const float*)d_in[12];
    const float* bn1b  = (const float*)d_in[13];
    const float* bn2g  = (const float*)d_in[14];
    const float* bn2b  = (const float*)d_in[15];
    const float* wq    = (const float*)d_in[16];
    const float* bq    = (const float*)d_in[17];
    const float* wk    = (const float*)d_in[18];
    const float* bk    = (const float*)d_in[19];
    const float* wv    = (const float*)d_in[20];
    const float* bv    = (const float*)d_in[21];
    const float* gamma = (const float*)d_in[22];
    float* out = (float*)d_out;

    char* ws = (char*)d_ws;
    float* te    = (float*)(ws + 0);
    float* sums  = (float*)(ws + 16384);
    float* scale = (float*)(ws + 18432);
    float* shift = (float*)(ws + 19456);
    char* base = ws + 32768;
    bf16* W3_1 = (bf16*)(base);
    bf16* W3_2 = (bf16*)(base + 1179648);
    bf16* W3_3 = (bf16*)(base + 2359296);
    bf16* Xp0  = (bf16*)(base + 3538944);
    bf16* Xp1  = (bf16*)(base + 13008896);
    bf16* Craw = (bf16*)(base + 22478848);
    bf16* P    = (bf16*)(base);                    // 32 MB alias
    bf16* Yt   = (bf16*)(base + 33554432);
    bf16* QKb  = (bf16*)(base + 41943040);
    bf16* Vb   = (bf16*)(base + 44040192);
    float* invs= (float*)(base + 52428800);
    bf16* WQK  = (bf16*)(base + 52494336);
    bf16* WVb  = (bf16*)(base + 52527104);

    const unsigned int XP_U32 = 16u * 1156u * 256u / 2u;

    zero_k<<<2048, 256, 0, stream>>>((unsigned int*)Xp0, XP_U32);
    zero_k<<<2048, 256, 0, stream>>>((unsigned int*)Xp1, XP_U32);
    zero_k<<<2, 256, 0, stream>>>((unsigned int*)sums, 512);
    time_mlp_k<<<16, 256, 0, stream>>>(t, w_t1, b_t1, w_t2, b_t2, te);
    prep_w_k<<<2304, 256, 0, stream>>>(w_c1, W3_1);
    prep_w_k<<<2304, 256, 0, stream>>>(w_c2, W3_2);
    prep_w_k<<<2304, 256, 0, stream>>>(w_tr, W3_3);
    prep_wqk_k<<<64, 256, 0, stream>>>(wq, wk, WQK);
    prep_wv_k<<<256, 256, 0, stream>>>(wv, WVb);
    prep_x_k<<<1024, 256, 0, stream>>>(x, Xp0);

    conv_mfma_k<true><<<256, 256, 0, stream>>>(Xp0, W3_1, b_c1, Craw);
    bn_stats_T_k<<<256, 256, 0, stream>>>(Craw, sums);
    bn_fin_k<<<1, 256, 0, stream>>>(sums, bn1g, bn1b, scale, shift);
    bn_apply_T_k<true><<<2048, 256, 0, stream>>>(Craw, scale, shift, te, Xp1);

    zero_k<<<2, 256, 0, stream>>>((unsigned int*)sums, 512);
    conv_mfma_k<true><<<256, 256, 0, stream>>>(Xp1, W3_2, b_c2, Craw);
    bn_stats_T_k<<<256, 256, 0, stream>>>(Craw, sums);
    bn_fin_k<<<1, 256, 0, stream>>>(sums, bn2g, bn2b, scale, shift);
    bn_apply_T_k<false><<<2048, 256, 0, stream>>>(Craw, scale, shift, nullptr, Xp0);

    conv_mfma_k<false><<<256, 256, 0, stream>>>(Xp0, W3_3, b_tr, Yt);

    qk_mfma_k<<<256, 256, 0, stream>>>(Yt, WQK, bq, bk, QKb);
    v_mfma_k<<<256, 256, 0, stream>>>(WVb, Yt, bv, Vb);
    softmax_k<<<512, 256, 0, stream>>>(QKb, P, invs);
    pv_mfma_k<<<256, 256, 0, stream>>>(Vb, P, invs, Yt, gamma, out);
}

// Round 6
// 244.234 us; speedup vs baseline: 17.7405x; 1.0900x over previous
//
#include <hip/hip_runtime.h>
#include <hip/hip_bf16.h>

using bf16 = __hip_bfloat16;

typedef __attribute__((ext_vector_type(8))) short bf16x8_t;
typedef __attribute__((ext_vector_type(4))) float f32x4_t;

__device__ __forceinline__ float b2f(bf16 x){ return __bfloat162float(x); }
__device__ __forceinline__ bf16  f2b(float x){ return __float2bfloat16(x); }
__device__ __forceinline__ unsigned short f2bu(float x){ bf16 h = __float2bfloat16(x); return *(unsigned short*)&h; }
__device__ __forceinline__ float bits2f(unsigned int lo16){ return __uint_as_float(lo16 << 16); }

__device__ __forceinline__ void gload16(const void* g, void* l) {
    __builtin_amdgcn_global_load_lds(
        (const __attribute__((address_space(1))) unsigned int*)g,
        (__attribute__((address_space(3))) unsigned int*)l, 16, 0, 0);
}

// ---------------------------------------------------------------------------
// Dims: B=16, C=256, H=W=32, N=1024, padded P=34x34=1156, Cq=32
// GEMM tiling (conv/v/pv): 64(M) x 128(N) tile, BK=64, 4 waves as 2Mx2N,
// each wave 32x64 -> acc[2][4]. Double-buffered LDS + counted vmcnt(6).
// Stage = 6 gload16/thread (A: 2, B: 4).
// ---------------------------------------------------------------------------

__global__ void zero_k(unsigned int* __restrict__ p, unsigned int n) {
    for (unsigned int i = blockIdx.x * 256 + threadIdx.x; i < n; i += gridDim.x * 256) p[i] = 0u;
}

__global__ __launch_bounds__(256) void time_mlp_k(
    const float* __restrict__ t, const float* __restrict__ w1, const float* __restrict__ b1,
    const float* __restrict__ w2, const float* __restrict__ b2, float* __restrict__ te)
{
    const int b = blockIdx.x, j = threadIdx.x;
    __shared__ float tr[256], hid[256];
    tr[j] = t[(b << 8) + j];
    __syncthreads();
    float s = b1[j];
    const float* wp = w1 + j * 256;
    for (int k = 0; k < 256; ++k) s += tr[k] * wp[k];
    hid[j] = fmaxf(s, 0.f);
    __syncthreads();
    float s2 = b2[j];
    const float* wp2 = w2 + j * 256;
    for (int k = 0; k < 256; ++k) s2 += hid[k] * wp2[k];
    te[(b << 8) + j] = fmaxf(s2, 0.f);
}

__global__ __launch_bounds__(256) void prep_w_k(const float* __restrict__ w, bf16* __restrict__ W3)
{
    const int blk = blockIdx.x;            // co*9 + off
    const int ci = threadIdx.x;
    const int co = blk / 9, off = blk % 9;
    W3[(size_t)blk * 256 + ci] = f2b(w[(size_t)co * 2304 + ci * 9 + off]);
}

__global__ __launch_bounds__(256) void prep_wqk_k(
    const float* __restrict__ wq, const float* __restrict__ wk, bf16* __restrict__ WQK)
{
    const int r = blockIdx.x, c = threadIdx.x;
    const float v = (r < 32) ? wq[r * 256 + c] : wk[(r - 32) * 256 + c];
    WQK[r * 256 + c] = f2b(v);
}

__global__ __launch_bounds__(256) void prep_wv_k(const float* __restrict__ wv, bf16* __restrict__ WVb)
{
    const int r = blockIdx.x, c = threadIdx.x;
    WVb[r * 256 + c] = f2b(wv[r * 256 + c]);
}

// x fp32 [b][c][n] -> Xp bf16 [b][1156][c]
__global__ __launch_bounds__(256) void prep_x_k(const float* __restrict__ x, bf16* __restrict__ Xp)
{
    __shared__ float xs[64][65];
    const int t = threadIdx.x;
    const int b = blockIdx.x >> 6, ct = (blockIdx.x >> 4) & 3, nt = blockIdx.x & 15;
    const int c0 = ct << 6, n0 = nt << 6;
    {
        const int cl = t >> 2, nc = (t & 3) << 4;
        const float* src = x + (size_t)((b << 8) + c0 + cl) * 1024 + n0 + nc;
        #pragma unroll
        for (int j = 0; j < 16; j += 4) {
            const float4 v = *(const float4*)(src + j);
            xs[cl][nc + j] = v.x; xs[cl][nc + j + 1] = v.y;
            xs[cl][nc + j + 2] = v.z; xs[cl][nc + j + 3] = v.w;
        }
    }
    __syncthreads();
    {
        const int nl = t >> 2, cc = (t & 3) << 4;
        const int n = n0 + nl;
        const int p = ((n >> 5) + 1) * 34 + (n & 31) + 1;
        unsigned int u[8];
        #pragma unroll
        for (int k = 0; k < 8; ++k)
            u[k] = (unsigned int)f2bu(xs[cc + 2 * k][nl]) | ((unsigned int)f2bu(xs[cc + 2 * k + 1][nl]) << 16);
        bf16* dst = Xp + (size_t)(b * 1156 + p) * 256 + c0 + cc;
        *(uint4*)dst = make_uint4(u[0], u[1], u[2], u[3]);
        *(uint4*)(dst + 8) = make_uint4(u[4], u[5], u[6], u[7]);
    }
}

// ---- conv3x3 implicit GEMM: 64x128 tile, dbuf, counted vmcnt ----
template<bool RELU>
__global__ __launch_bounds__(256, 2) void conv_mfma_k(
    const bf16* __restrict__ Xp, const bf16* __restrict__ W3,
    const float* __restrict__ bias, bf16* __restrict__ outp)
{
    __shared__ bf16 Als[2][64 * 64];
    __shared__ bf16 Bls[2][128 * 64];
    const int tid = threadIdx.x;
    const int wid = tid >> 6, lane = tid & 63;
    const int wm = wid >> 1, wn = wid & 1;
    const int blk = blockIdx.x;
    const int b = blk >> 5, mt = (blk >> 1) & 15, nt = blk & 1;
    const int m0 = mt << 6, co0 = nt << 7;

    const int lr = lane >> 3;
    const int sL8 = (((lane & 7) ^ lr) << 3);

    const bf16* agp[2];
    #pragma unroll
    for (int i = 0; i < 2; ++i) {
        const int r = (((i << 2) + wid) << 3) + lr;
        const int n = m0 + r;
        const int pb = (n >> 5) * 34 + (n & 31);
        agp[i] = Xp + (size_t)(b * 1156 + pb) * 256 + sL8;
    }
    const bf16* bgp[4];
    #pragma unroll
    for (int i = 0; i < 4; ++i) {
        const int r = (((i << 2) + wid) << 3) + lr;
        bgp[i] = W3 + (size_t)(co0 + r) * 2304 + sL8;
    }

    const int rsel = lane & 15;
    const int s0 = (((lane >> 4) ^ (lane & 7)) << 3);
    const int s1 = ((((lane >> 4) + 4) ^ (lane & 7)) << 3);
    const int arow = ((wm << 5) + rsel) << 6;
    const int brow = ((wn << 6) + rsel) << 6;

    f32x4_t acc[2][4];
    #pragma unroll
    for (int mi = 0; mi < 2; ++mi)
        #pragma unroll
        for (int ni = 0; ni < 4; ++ni)
            acc[mi][ni] = (f32x4_t){0.f, 0.f, 0.f, 0.f};

    #define CONV_STAGE(KT, BUF) {                                            \
        const int off_ = (KT) >> 2, cic_ = (KT) & 3;                          \
        const int kh_ = (off_ * 11) >> 5;                                     \
        const int doff_ = ((off_ + 31 * kh_) << 8) + (cic_ << 6);             \
        const int koff_ = (off_ << 8) + (cic_ << 6);                          \
        _Pragma("unroll")                                                     \
        for (int i = 0; i < 2; ++i)                                           \
            gload16(agp[i] + doff_, &Als[BUF][(((i << 2) + wid) << 9)]);      \
        _Pragma("unroll")                                                     \
        for (int i = 0; i < 4; ++i)                                           \
            gload16(bgp[i] + koff_, &Bls[BUF][(((i << 2) + wid) << 9)]);      \
    }

    CONV_STAGE(0, 0);
    for (int kt = 0; kt < 36; ++kt) {
        const int cur = kt & 1;
        if (kt + 1 < 36) {
            CONV_STAGE(kt + 1, cur ^ 1);
            asm volatile("s_waitcnt vmcnt(6)" ::: "memory");
        } else {
            asm volatile("s_waitcnt vmcnt(0)" ::: "memory");
        }
        __builtin_amdgcn_s_barrier();
        asm volatile("" ::: "memory");
        #pragma unroll
        for (int kh = 0; kh < 2; ++kh) {
            const int sk = kh ? s1 : s0;
            bf16x8_t av[2], bv[4];
            #pragma unroll
            for (int mi = 0; mi < 2; ++mi)
                av[mi] = *(const bf16x8_t*)(&Als[cur][arow + (mi << 10) + sk]);
            #pragma unroll
            for (int ni = 0; ni < 4; ++ni)
                bv[ni] = *(const bf16x8_t*)(&Bls[cur][brow + (ni << 10) + sk]);
            #pragma unroll
            for (int mi = 0; mi < 2; ++mi)
                #pragma unroll
                for (int ni = 0; ni < 4; ++ni)
                    acc[mi][ni] = __builtin_amdgcn_mfma_f32_16x16x32_bf16(
                        av[mi], bv[ni], acc[mi][ni], 0, 0, 0);
        }
        __builtin_amdgcn_s_barrier();
        asm volatile("" ::: "memory");
    }
    #undef CONV_STAGE

    const int cr = (lane >> 4) << 2;
    const int cc = lane & 15;
    #pragma unroll
    for (int ni = 0; ni < 4; ++ni) {
        const int co = co0 + (wn << 6) + (ni << 4) + cc;
        const float bb = bias[co];
        #pragma unroll
        for (int mi = 0; mi < 2; ++mi) {
            const int n = m0 + (wm << 5) + (mi << 4) + cr;
            #pragma unroll
            for (int j = 0; j < 4; ++j) {
                float v = acc[mi][ni][j] + bb;
                if (RELU) v = fmaxf(v, 0.f);
                outp[(size_t)((b << 10) + n + j) * 256 + co] = f2b(v);
            }
        }
    }
}

// bn stats over pixel-major Craw [16384][256]
__global__ __launch_bounds__(256) void bn_stats_T_k(
    const bf16* __restrict__ a, float* __restrict__ sums)
{
    __shared__ float ls[256], lq[256];
    const int t = threadIdx.x;
    ls[t] = 0.f; lq[t] = 0.f;
    __syncthreads();
    const int g = t >> 5, c0 = (t & 31) << 3;
    float s[8] = {0,0,0,0,0,0,0,0}, q[8] = {0,0,0,0,0,0,0,0};
    const int rbase = blockIdx.x * 64;
    for (int rr = g; rr < 64; rr += 8) {
        const uint4 u = *(const uint4*)(a + (size_t)(rbase + rr) * 256 + c0);
        const unsigned int w[4] = {u.x, u.y, u.z, u.w};
        #pragma unroll
        for (int k = 0; k < 4; ++k) {
            const float v0 = bits2f(w[k] & 0xffffu);
            const float v1 = __uint_as_float(w[k] & 0xffff0000u);
            s[2 * k] += v0; q[2 * k] += v0 * v0;
            s[2 * k + 1] += v1; q[2 * k + 1] += v1 * v1;
        }
    }
    #pragma unroll
    for (int j = 0; j < 8; ++j) {
        atomicAdd(&ls[c0 + j], s[j]);
        atomicAdd(&lq[c0 + j], q[j]);
    }
    __syncthreads();
    atomicAdd(&sums[t], ls[t]);
    atomicAdd(&sums[256 + t], lq[t]);
}

__global__ __launch_bounds__(256) void bn_fin_k(
    const float* __restrict__ sums, const float* __restrict__ g, const float* __restrict__ bb,
    float* __restrict__ scale, float* __restrict__ shift)
{
    const int c = threadIdx.x;
    const float m = sums[c] * (1.f / 16384.f);
    const float var = sums[256 + c] * (1.f / 16384.f) - m * m;
    const float sc = g[c] * rsqrtf(var + 1e-5f);
    scale[c] = sc; shift[c] = bb[c] - m * sc;
}

template<bool TE>
__global__ __launch_bounds__(256) void bn_apply_T_k(
    const bf16* __restrict__ a, const float* __restrict__ scale,
    const float* __restrict__ shift, const float* __restrict__ te,
    bf16* __restrict__ Xp)
{
    const int t = threadIdx.x;
    const int row = blockIdx.x * 8 + (t >> 5);
    const int c0 = (t & 31) << 3;
    const int b = row >> 10, n = row & 1023;
    const uint4 u = *(const uint4*)(a + (size_t)row * 256 + c0);
    const unsigned int w[4] = {u.x, u.y, u.z, u.w};
    const float4 sc0 = *(const float4*)(scale + c0);
    const float4 sc1 = *(const float4*)(scale + c0 + 4);
    const float4 sh0 = *(const float4*)(shift + c0);
    const float4 sh1 = *(const float4*)(shift + c0 + 4);
    const float scv[8] = {sc0.x, sc0.y, sc0.z, sc0.w, sc1.x, sc1.y, sc1.z, sc1.w};
    const float shv[8] = {sh0.x, sh0.y, sh0.z, sh0.w, sh1.x, sh1.y, sh1.z, sh1.w};
    float tev[8] = {0,0,0,0,0,0,0,0};
    if (TE) {
        const float4 t0 = *(const float4*)(te + (b << 8) + c0);
        const float4 t1 = *(const float4*)(te + (b << 8) + c0 + 4);
        tev[0]=t0.x; tev[1]=t0.y; tev[2]=t0.z; tev[3]=t0.w;
        tev[4]=t1.x; tev[5]=t1.y; tev[6]=t1.z; tev[7]=t1.w;
    }
    unsigned int o[4];
    #pragma unroll
    for (int k = 0; k < 4; ++k) {
        const float v0 = bits2f(w[k] & 0xffffu) * scv[2*k] + shv[2*k] + tev[2*k];
        const float v1 = __uint_as_float(w[k] & 0xffff0000u) * scv[2*k+1] + shv[2*k+1] + tev[2*k+1];
        o[k] = (unsigned int)f2bu(v0) | ((unsigned int)f2bu(v1) << 16);
    }
    const int p = ((n >> 5) + 1) * 34 + (n & 31) + 1;
    *(uint4*)(Xp + (size_t)(b * 1156 + p) * 256 + c0) = make_uint4(o[0], o[1], o[2], o[3]);
}

// Q|K projection (unchanged)
__global__ __launch_bounds__(256) void qk_mfma_k(
    const bf16* __restrict__ Yt, const bf16* __restrict__ WQK,
    const float* __restrict__ bq, const float* __restrict__ bk, bf16* __restrict__ QKb)
{
    const int b = blockIdx.x >> 4, m0 = (blockIdx.x & 15) << 6;
    const int tid = threadIdx.x, wid = tid >> 6, lane = tid & 63;
    const int n0w = m0 + (wid << 4);
    const bf16* arow = Yt + (size_t)((b << 10) + n0w + (lane & 15)) * 256 + ((lane >> 4) << 3);
    const int boff = ((lane >> 4) << 3);
    f32x4_t acc[4];
    #pragma unroll
    for (int ni = 0; ni < 4; ++ni) acc[ni] = (f32x4_t){0.f,0.f,0.f,0.f};
    for (int k0 = 0; k0 < 256; k0 += 32) {
        const bf16x8_t av = *(const bf16x8_t*)(arow + k0);
        #pragma unroll
        for (int ni = 0; ni < 4; ++ni) {
            const bf16x8_t bv = *(const bf16x8_t*)(WQK + (ni * 16 + (lane & 15)) * 256 + k0 + boff);
            acc[ni] = __builtin_amdgcn_mfma_f32_16x16x32_bf16(av, bv, acc[ni], 0, 0, 0);
        }
    }
    const int cr = (lane >> 4) << 2, cc = lane & 15;
    #pragma unroll
    for (int ni = 0; ni < 4; ++ni) {
        const int q = ni * 16 + cc;
        const float bias = (q < 32) ? bq[q] : bk[q - 32];
        #pragma unroll
        for (int j = 0; j < 4; ++j) {
            const int n = n0w + cr + j;
            QKb[(size_t)((b << 10) + n) * 64 + q] = f2b(acc[ni][j] + bias);
        }
    }
}

// V projection: Vb[b][v][n], 64x128 tile, dbuf, counted vmcnt. K=256 (4 steps).
__global__ __launch_bounds__(256, 2) void v_mfma_k(
    const bf16* __restrict__ WVb, const bf16* __restrict__ Yt,
    const float* __restrict__ bvp, bf16* __restrict__ Vb)
{
    __shared__ bf16 Als[2][64 * 64];
    __shared__ bf16 Bls[2][128 * 64];
    const int tid = threadIdx.x;
    const int wid = tid >> 6, lane = tid & 63;
    const int wm = wid >> 1, wn = wid & 1;
    const int blk = blockIdx.x;
    const int b = blk >> 5, vt = (blk >> 3) & 3, nt = blk & 7;
    const int v0 = vt << 6, n0 = nt << 7;

    const int lr = lane >> 3;
    const int sL8 = (((lane & 7) ^ lr) << 3);
    const bf16* agp[2];
    #pragma unroll
    for (int i = 0; i < 2; ++i) {
        const int r = (((i << 2) + wid) << 3) + lr;
        agp[i] = WVb + (size_t)(v0 + r) * 256 + sL8;
    }
    const bf16* bgp[4];
    #pragma unroll
    for (int i = 0; i < 4; ++i) {
        const int r = (((i << 2) + wid) << 3) + lr;
        bgp[i] = Yt + (size_t)((b << 10) + n0 + r) * 256 + sL8;
    }
    const int rsel = lane & 15;
    const int s0 = (((lane >> 4) ^ (lane & 7)) << 3);
    const int s1 = ((((lane >> 4) + 4) ^ (lane & 7)) << 3);
    const int arow = ((wm << 5) + rsel) << 6;
    const int brow = ((wn << 6) + rsel) << 6;

    f32x4_t acc[2][4];
    #pragma unroll
    for (int mi = 0; mi < 2; ++mi)
        #pragma unroll
        for (int ni = 0; ni < 4; ++ni)
            acc[mi][ni] = (f32x4_t){0.f,0.f,0.f,0.f};

    #define GEMM_STAGE(KOFF, BUF) {                                          \
        _Pragma("unroll")                                                     \
        for (int i = 0; i < 2; ++i)                                           \
            gload16(agp[i] + (KOFF), &Als[BUF][(((i << 2) + wid) << 9)]);     \
        _Pragma("unroll")                                                     \
        for (int i = 0; i < 4; ++i)                                           \
            gload16(bgp[i] + (KOFF), &Bls[BUF][(((i << 2) + wid) << 9)]);     \
    }

    GEMM_STAGE(0, 0);
    for (int kt = 0; kt < 4; ++kt) {
        const int cur = kt & 1;
        if (kt + 1 < 4) {
            GEMM_STAGE((kt + 1) << 6, cur ^ 1);
            asm volatile("s_waitcnt vmcnt(6)" ::: "memory");
        } else {
            asm volatile("s_waitcnt vmcnt(0)" ::: "memory");
        }
        __builtin_amdgcn_s_barrier();
        asm volatile("" ::: "memory");
        #pragma unroll
        for (int kh = 0; kh < 2; ++kh) {
            const int sk = kh ? s1 : s0;
            bf16x8_t av[2], bv[4];
            #pragma unroll
            for (int mi = 0; mi < 2; ++mi)
                av[mi] = *(const bf16x8_t*)(&Als[cur][arow + (mi << 10) + sk]);
            #pragma unroll
            for (int ni = 0; ni < 4; ++ni)
                bv[ni] = *(const bf16x8_t*)(&Bls[cur][brow + (ni << 10) + sk]);
            #pragma unroll
            for (int mi = 0; mi < 2; ++mi)
                #pragma unroll
                for (int ni = 0; ni < 4; ++ni)
                    acc[mi][ni] = __builtin_amdgcn_mfma_f32_16x16x32_bf16(
                        av[mi], bv[ni], acc[mi][ni], 0, 0, 0);
        }
        __builtin_amdgcn_s_barrier();
        asm volatile("" ::: "memory");
    }

    const int cr = (lane >> 4) << 2, cc = lane & 15;
    #pragma unroll
    for (int mi = 0; mi < 2; ++mi) {
        #pragma unroll
        for (int j = 0; j < 4; ++j) {
            const int v = v0 + (wm << 5) + (mi << 4) + cr + j;
            const float bb = bvp[v];
            #pragma unroll
            for (int ni = 0; ni < 4; ++ni) {
                const int n = n0 + (wn << 6) + (ni << 4) + cc;
                Vb[(size_t)((b << 8) + v) * 1024 + n] = f2b(acc[mi][ni][j] + bb);
            }
        }
    }
}

// scores + softmax (unchanged)
__global__ __launch_bounds__(256) void softmax_k(
    const bf16* __restrict__ QKb, bf16* __restrict__ P, float* __restrict__ invs)
{
    const int b = blockIdx.x >> 5, n0 = (blockIdx.x & 31) << 5;
    const int tid = threadIdx.x, wid = tid >> 6, lane = tid & 63;
    const int m0w = wid << 8;
    __shared__ float wred[4][32];

    const bf16* qbase = QKb + (size_t)((b << 10) + n0) * 64;
    const int koff = (lane >> 4) << 3;
    bf16x8_t qf[2];
    #pragma unroll
    for (int nt = 0; nt < 2; ++nt)
        qf[nt] = *(const bf16x8_t*)(qbase + (nt * 16 + (lane & 15)) * 64 + koff);
    const bf16* kbase = QKb + (size_t)(b << 10) * 64 + 32;

    float mx[2] = {-3.0e38f, -3.0e38f};
    for (int mi = 0; mi < 16; ++mi) {
        const bf16x8_t kf = *(const bf16x8_t*)(kbase + (m0w + mi * 16 + (lane & 15)) * 64 + koff);
        #pragma unroll
        for (int nt = 0; nt < 2; ++nt) {
            f32x4_t s = (f32x4_t){0.f,0.f,0.f,0.f};
            s = __builtin_amdgcn_mfma_f32_16x16x32_bf16(kf, qf[nt], s, 0, 0, 0);
            mx[nt] = fmaxf(mx[nt], fmaxf(fmaxf(s[0], s[1]), fmaxf(s[2], s[3])));
        }
    }
    #pragma unroll
    for (int nt = 0; nt < 2; ++nt) {
        mx[nt] = fmaxf(mx[nt], __shfl_xor(mx[nt], 16));
        mx[nt] = fmaxf(mx[nt], __shfl_xor(mx[nt], 32));
        if (lane < 16) wred[wid][nt * 16 + lane] = mx[nt];
    }
    __syncthreads();
    float rm[2];
    #pragma unroll
    for (int nt = 0; nt < 2; ++nt) {
        const int c = nt * 16 + (lane & 15);
        rm[nt] = fmaxf(fmaxf(wred[0][c], wred[1][c]), fmaxf(wred[2][c], wred[3][c]));
    }
    __syncthreads();

    float sm[2] = {0.f, 0.f};
    for (int mi = 0; mi < 16; ++mi) {
        const bf16x8_t kf = *(const bf16x8_t*)(kbase + (m0w + mi * 16 + (lane & 15)) * 64 + koff);
        #pragma unroll
        for (int nt = 0; nt < 2; ++nt) {
            f32x4_t s = (f32x4_t){0.f,0.f,0.f,0.f};
            s = __builtin_amdgcn_mfma_f32_16x16x32_bf16(kf, qf[nt], s, 0, 0, 0);
            const float p0 = __expf(s[0] - rm[nt]);
            const float p1 = __expf(s[1] - rm[nt]);
            const float p2 = __expf(s[2] - rm[nt]);
            const float p3 = __expf(s[3] - rm[nt]);
            sm[nt] += (p0 + p1) + (p2 + p3);
            uint2 u;
            u.x = (unsigned int)f2bu(p0) | ((unsigned int)f2bu(p1) << 16);
            u.y = (unsigned int)f2bu(p2) | ((unsigned int)f2bu(p3) << 16);
            const int n = n0 + nt * 16 + (lane & 15);
            const int m = m0w + mi * 16 + ((lane >> 4) << 2);
            *(uint2*)(P + (size_t)((b << 10) + n) * 1024 + m) = u;
        }
    }
    #pragma unroll
    for (int nt = 0; nt < 2; ++nt) {
        sm[nt] += __shfl_xor(sm[nt], 16);
        sm[nt] += __shfl_xor(sm[nt], 32);
        if (lane < 16) wred[wid][nt * 16 + lane] = sm[nt];
    }
    __syncthreads();
    if (tid < 32) {
        const float total = wred[0][tid] + wred[1][tid] + wred[2][tid] + wred[3][tid];
        invs[(b << 10) + n0 + tid] = 1.f / total;
    }
}

// PV + residual: 64x128 tile, dbuf, counted vmcnt. K=1024 (16 steps).
__global__ __launch_bounds__(256, 2) void pv_mfma_k(
    const bf16* __restrict__ Vb, const bf16* __restrict__ P,
    const float* __restrict__ invs, const bf16* __restrict__ Yt,
    const float* __restrict__ gamma, float* __restrict__ out)
{
    __shared__ bf16 Als[2][64 * 64];
    __shared__ bf16 Bls[2][128 * 64];
    const int tid = threadIdx.x;
    const int wid = tid >> 6, lane = tid & 63;
    const int wm = wid >> 1, wn = wid & 1;
    const int blk = blockIdx.x;
    const int b = blk >> 5, ct = (blk >> 3) & 3, nt = blk & 7;
    const int c0 = ct << 6, n0 = nt << 7;

    const int lr = lane >> 3;
    const int sL8 = (((lane & 7) ^ lr) << 3);
    const bf16* agp[2];
    #pragma unroll
    for (int i = 0; i < 2; ++i) {
        const int r = (((i << 2) + wid) << 3) + lr;
        agp[i] = Vb + (size_t)((b << 8) + c0 + r) * 1024 + sL8;
    }
    const bf16* bgp[4];
    #pragma unroll
    for (int i = 0; i < 4; ++i) {
        const int r = (((i << 2) + wid) << 3) + lr;
        bgp[i] = P + (size_t)((b << 10) + n0 + r) * 1024 + sL8;
    }
    const int rsel = lane & 15;
    const int s0 = (((lane >> 4) ^ (lane & 7)) << 3);
    const int s1 = ((((lane >> 4) + 4) ^ (lane & 7)) << 3);
    const int arow = ((wm << 5) + rsel) << 6;
    const int brow = ((wn << 6) + rsel) << 6;

    f32x4_t acc[2][4];
    #pragma unroll
    for (int mi = 0; mi < 2; ++mi)
        #pragma unroll
        for (int ni = 0; ni < 4; ++ni)
            acc[mi][ni] = (f32x4_t){0.f,0.f,0.f,0.f};

    GEMM_STAGE(0, 0);
    for (int kt = 0; kt < 16; ++kt) {
        const int cur = kt & 1;
        if (kt + 1 < 16) {
            GEMM_STAGE((kt + 1) << 6, cur ^ 1);
            asm volatile("s_waitcnt vmcnt(6)" ::: "memory");
        } else {
            asm volatile("s_waitcnt vmcnt(0)" ::: "memory");
        }
        __builtin_amdgcn_s_barrier();
        asm volatile("" ::: "memory");
        #pragma unroll
        for (int kh = 0; kh < 2; ++kh) {
            const int sk = kh ? s1 : s0;
            bf16x8_t av[2], bv[4];
            #pragma unroll
            for (int mi = 0; mi < 2; ++mi)
                av[mi] = *(const bf16x8_t*)(&Als[cur][arow + (mi << 10) + sk]);
            #pragma unroll
            for (int ni = 0; ni < 4; ++ni)
                bv[ni] = *(const bf16x8_t*)(&Bls[cur][brow + (ni << 10) + sk]);
            #pragma unroll
            for (int mi = 0; mi < 2; ++mi)
                #pragma unroll
                for (int ni = 0; ni < 4; ++ni)
                    acc[mi][ni] = __builtin_amdgcn_mfma_f32_16x16x32_bf16(
                        av[mi], bv[ni], acc[mi][ni], 0, 0, 0);
        }
        __builtin_amdgcn_s_barrier();
        asm volatile("" ::: "memory");
    }
    #undef GEMM_STAGE

    const float g = gamma[0];
    const int cr = (lane >> 4) << 2, cc = lane & 15;
    #pragma unroll
    for (int ni = 0; ni < 4; ++ni) {
        const int n = n0 + (wn << 6) + (ni << 4) + cc;
        const float gi = g * invs[(b << 10) + n];
        #pragma unroll
        for (int mi = 0; mi < 2; ++mi) {
            const int c = c0 + (wm << 5) + (mi << 4) + cr;
            const bf16* yp = Yt + (size_t)((b << 10) + n) * 256 + c;
            #pragma unroll
            for (int j = 0; j < 4; ++j)
                out[(size_t)((b << 8) + c + j) * 1024 + n] = gi * acc[mi][ni][j] + b2f(yp[j]);
        }
    }
}

// ---------------------------------------------------------------------------
// Workspace layout: identical to round 5 (~52.7 MB, P aliases dead conv bufs)
// ---------------------------------------------------------------------------
extern "C" void kernel_launch(void* const* d_in, const int* in_sizes, int n_in,
                              void* d_out, int out_size, void* d_ws, size_t ws_size,
                              hipStream_t stream)
{
    const float* x     = (const float*)d_in[0];
    const float* t     = (const float*)d_in[1];
    const float* w_t1  = (const float*)d_in[2];
    const float* b_t1  = (const float*)d_in[3];
    const float* w_t2  = (const float*)d_in[4];
    const float* b_t2  = (const float*)d_in[5];
    const float* w_c1  = (const float*)d_in[6];
    const float* b_c1  = (const float*)d_in[7];
    const float* w_c2  = (const float*)d_in[8];
    const float* b_c2  = (const float*)d_in[9];
    const float* w_tr  = (const float*)d_in[10];
    const float* b_tr  = (const float*)d_in[11];
    const float* bn1g  = (const float*)d_in[12];
    const float* bn1b  = (const float*)d_in[13];
    const float* bn2g  = (const float*)d_in[14];
    const float* bn2b  = (const float*)d_in[15];
    const float* wq    = (const float*)d_in[16];
    const float* bq    = (const float*)d_in[17];
    const float* wk    = (const float*)d_in[18];
    const float* bk    = (const float*)d_in[19];
    const float* wv    = (const float*)d_in[20];
    const float* bv    = (const float*)d_in[21];
    const float* gamma = (const float*)d_in[22];
    float* out = (float*)d_out;

    char* ws = (char*)d_ws;
    float* te    = (float*)(ws + 0);
    float* sums  = (float*)(ws + 16384);
    float* scale = (float*)(ws + 18432);
    float* shift = (float*)(ws + 19456);
    char* base = ws + 32768;
    bf16* W3_1 = (bf16*)(base);
    bf16* W3_2 = (bf16*)(base + 1179648);
    bf16* W3_3 = (bf16*)(base + 2359296);
    bf16* Xp0  = (bf16*)(base + 3538944);
    bf16* Xp1  = (bf16*)(base + 13008896);
    bf16* Craw = (bf16*)(base + 22478848);
    bf16* P    = (bf16*)(base);                    // 32 MB alias
    bf16* Yt   = (bf16*)(base + 33554432);
    bf16* QKb  = (bf16*)(base + 41943040);
    bf16* Vb   = (bf16*)(base + 44040192);
    float* invs= (float*)(base + 52428800);
    bf16* WQK  = (bf16*)(base + 52494336);
    bf16* WVb  = (bf16*)(base + 52527104);

    const unsigned int XP_U32 = 16u * 1156u * 256u / 2u;

    zero_k<<<2048, 256, 0, stream>>>((unsigned int*)Xp0, XP_U32);
    zero_k<<<2048, 256, 0, stream>>>((unsigned int*)Xp1, XP_U32);
    zero_k<<<2, 256, 0, stream>>>((unsigned int*)sums, 512);
    time_mlp_k<<<16, 256, 0, stream>>>(t, w_t1, b_t1, w_t2, b_t2, te);
    prep_w_k<<<2304, 256, 0, stream>>>(w_c1, W3_1);
    prep_w_k<<<2304, 256, 0, stream>>>(w_c2, W3_2);
    prep_w_k<<<2304, 256, 0, stream>>>(w_tr, W3_3);
    prep_wqk_k<<<64, 256, 0, stream>>>(wq, wk, WQK);
    prep_wv_k<<<256, 256, 0, stream>>>(wv, WVb);
    prep_x_k<<<1024, 256, 0, stream>>>(x, Xp0);

    conv_mfma_k<true><<<512, 256, 0, stream>>>(Xp0, W3_1, b_c1, Craw);
    bn_stats_T_k<<<256, 256, 0, stream>>>(Craw, sums);
    bn_fin_k<<<1, 256, 0, stream>>>(sums, bn1g, bn1b, scale, shift);
    bn_apply_T_k<true><<<2048, 256, 0, stream>>>(Craw, scale, shift, te, Xp1);

    zero_k<<<2, 256, 0, stream>>>((unsigned int*)sums, 512);
    conv_mfma_k<true><<<512, 256, 0, stream>>>(Xp1, W3_2, b_c2, Craw);
    bn_stats_T_k<<<256, 256, 0, stream>>>(Craw, sums);
    bn_fin_k<<<1, 256, 0, stream>>>(sums, bn2g, bn2b, scale, shift);
    bn_apply_T_k<false><<<2048, 256, 0, stream>>>(Craw, scale, shift, nullptr, Xp0);

    conv_mfma_k<false><<<512, 256, 0, stream>>>(Xp0, W3_3, b_tr, Yt);

    qk_mfma_k<<<256, 256, 0, stream>>>(Yt, WQK, bq, bk, QKb);
    v_mfma_k<<<512, 256, 0, stream>>>(WVb, Yt, bv, Vb);
    softmax_k<<<512, 256, 0, stream>>>(QKb, P, invs);
    pv_mfma_k<<<512, 256, 0, stream>>>(Vb, P, invs, Yt, gamma, out);
}

// Round 7
// 203.950 us; speedup vs baseline: 21.2447x; 1.1975x over previous
//
#include <hip/hip_runtime.h>
#include <hip/hip_bf16.h>

using bf16 = __hip_bfloat16;

typedef __attribute__((ext_vector_type(8))) short bf16x8_t;
typedef __attribute__((ext_vector_type(4))) float f32x4_t;

__device__ __forceinline__ float b2f(bf16 x){ return __bfloat162float(x); }
__device__ __forceinline__ bf16  f2b(float x){ return __float2bfloat16(x); }
__device__ __forceinline__ unsigned short f2bu(float x){ bf16 h = __float2bfloat16(x); return *(unsigned short*)&h; }
__device__ __forceinline__ float bits2f(unsigned int lo16){ return __uint_as_float(lo16 << 16); }

__device__ __forceinline__ void gload16(const void* g, void* l) {
    __builtin_amdgcn_global_load_lds(
        (const __attribute__((address_space(1))) unsigned int*)g,
        (__attribute__((address_space(3))) unsigned int*)l, 16, 0, 0);
}

// ---------------------------------------------------------------------------
// Dims: B=16, C=256, H=W=32, N=1024, padded P=34x34=1156, Cq=32
// conv/v GEMMs: 64x64 tile, BK=64, 4 waves (2Mx2N), 4 blocks/CU.
// pv GEMM: 64x128 tile, 2 blocks/CU. All double-buffered LDS + counted vmcnt.
// ---------------------------------------------------------------------------

__global__ void zero_k(unsigned int* __restrict__ p, unsigned int n) {
    for (unsigned int i = blockIdx.x * 256 + threadIdx.x; i < n; i += gridDim.x * 256) p[i] = 0u;
}

__global__ __launch_bounds__(256) void time_mlp_k(
    const float* __restrict__ t, const float* __restrict__ w1, const float* __restrict__ b1,
    const float* __restrict__ w2, const float* __restrict__ b2, float* __restrict__ te)
{
    const int b = blockIdx.x, j = threadIdx.x;
    __shared__ float tr[256], hid[256];
    tr[j] = t[(b << 8) + j];
    __syncthreads();
    float s = b1[j];
    const float* wp = w1 + j * 256;
    for (int k = 0; k < 256; ++k) s += tr[k] * wp[k];
    hid[j] = fmaxf(s, 0.f);
    __syncthreads();
    float s2 = b2[j];
    const float* wp2 = w2 + j * 256;
    for (int k = 0; k < 256; ++k) s2 += hid[k] * wp2[k];
    te[(b << 8) + j] = fmaxf(s2, 0.f);
}

// all three conv weights [co][ci][3][3] fp32 -> [co][off][ci] bf16 (LDS-staged, coalesced)
__global__ __launch_bounds__(256) void prep_w_all_k(
    const float* __restrict__ w1, const float* __restrict__ w2, const float* __restrict__ w3,
    bf16* __restrict__ W1, bf16* __restrict__ W2, bf16* __restrict__ W3o)
{
    __shared__ float ls[2304];
    const int t = threadIdx.x;
    const int co = blockIdx.x & 255;
    const int sel = blockIdx.x >> 8;
    const float* w = (sel == 0) ? w1 : (sel == 1) ? w2 : w3;
    bf16* dst = (sel == 0) ? W1 : (sel == 1) ? W2 : W3o;
    const float* src = w + (size_t)co * 2304;
    #pragma unroll
    for (int i = 0; i < 9; ++i) ls[t + (i << 8)] = src[t + (i << 8)];
    __syncthreads();
    #pragma unroll
    for (int off = 0; off < 9; ++off)
        dst[(size_t)(co * 9 + off) * 256 + t] = f2b(ls[t * 9 + off]);
}

// wq/wk -> WQK[64][256], wv -> WVb[256][256]
__global__ __launch_bounds__(256) void prep_wqkv_k(
    const float* __restrict__ wq, const float* __restrict__ wk, const float* __restrict__ wv,
    bf16* __restrict__ WQK, bf16* __restrict__ WVb)
{
    const int r = blockIdx.x, c = threadIdx.x;
    if (r < 32)       WQK[r * 256 + c] = f2b(wq[r * 256 + c]);
    else if (r < 64)  WQK[r * 256 + c] = f2b(wk[(r - 32) * 256 + c]);
    else              WVb[(r - 64) * 256 + c] = f2b(wv[(r - 64) * 256 + c]);
}

// x fp32 [b][c][n] -> Xp bf16 [b][1156][c]; block 0 also zeroes the bn sums (1024 f32)
__global__ __launch_bounds__(256) void prep_x_k(const float* __restrict__ x, bf16* __restrict__ Xp,
                                                float* __restrict__ sums)
{
    __shared__ float xs[64][65];
    const int t = threadIdx.x;
    if (blockIdx.x == 0) {
        sums[t] = 0.f; sums[t + 256] = 0.f; sums[t + 512] = 0.f; sums[t + 768] = 0.f;
    }
    const int b = blockIdx.x >> 6, ct = (blockIdx.x >> 4) & 3, nt = blockIdx.x & 15;
    const int c0 = ct << 6, n0 = nt << 6;
    {
        const int cl = t >> 2, nc = (t & 3) << 4;
        const float* src = x + (size_t)((b << 8) + c0 + cl) * 1024 + n0 + nc;
        #pragma unroll
        for (int j = 0; j < 16; j += 4) {
            const float4 v = *(const float4*)(src + j);
            xs[cl][nc + j] = v.x; xs[cl][nc + j + 1] = v.y;
            xs[cl][nc + j + 2] = v.z; xs[cl][nc + j + 3] = v.w;
        }
    }
    __syncthreads();
    {
        const int nl = t >> 2, cc = (t & 3) << 4;
        const int n = n0 + nl;
        const int p = ((n >> 5) + 1) * 34 + (n & 31) + 1;
        unsigned int u[8];
        #pragma unroll
        for (int k = 0; k < 8; ++k)
            u[k] = (unsigned int)f2bu(xs[cc + 2 * k][nl]) | ((unsigned int)f2bu(xs[cc + 2 * k + 1][nl]) << 16);
        bf16* dst = Xp + (size_t)(b * 1156 + p) * 256 + c0 + cc;
        *(uint4*)dst = make_uint4(u[0], u[1], u[2], u[3]);
        *(uint4*)(dst + 8) = make_uint4(u[4], u[5], u[6], u[7]);
    }
}

// ---- conv3x3 implicit GEMM: 64x64 tile, dbuf, vmcnt(4), fused bn-stats ----
template<bool RELU, bool STATS>
__global__ __launch_bounds__(256, 4) void conv_mfma_k(
    const bf16* __restrict__ Xp, const bf16* __restrict__ W3,
    const float* __restrict__ bias, bf16* __restrict__ outp, float* __restrict__ sums)
{
    __shared__ bf16 Als[2][64 * 64];
    __shared__ bf16 Bls[2][64 * 64];
    __shared__ float sstat[256];   // [wn][ni][cc] x {sum, sq}
    const int tid = threadIdx.x;
    const int wid = tid >> 6, lane = tid & 63;
    const int wm = wid >> 1, wn = wid & 1;
    const int blk = blockIdx.x;
    const int b = blk >> 6, mt = (blk >> 2) & 15, nt = blk & 3;
    const int m0 = mt << 6, co0 = nt << 6;

    if (STATS) { sstat[tid] = 0.f; }   // any later barrier orders this before epilogue

    const int lr = lane >> 3;
    const int sL8 = (((lane & 7) ^ lr) << 3);

    const bf16* agp[2]; const bf16* bgp[2];
    #pragma unroll
    for (int i = 0; i < 2; ++i) {
        const int r = (((i << 2) + wid) << 3) + lr;
        const int n = m0 + r;
        const int pb = (n >> 5) * 34 + (n & 31);
        agp[i] = Xp + (size_t)(b * 1156 + pb) * 256 + sL8;
        bgp[i] = W3 + (size_t)(co0 + r) * 2304 + sL8;
    }

    const int rsel = lane & 15;
    const int s0 = (((lane >> 4) ^ (lane & 7)) << 3);
    const int s1 = ((((lane >> 4) + 4) ^ (lane & 7)) << 3);
    const int arow = ((wm << 5) + rsel) << 6;
    const int brow = ((wn << 5) + rsel) << 6;

    f32x4_t acc[2][2];
    #pragma unroll
    for (int mi = 0; mi < 2; ++mi)
        #pragma unroll
        for (int ni = 0; ni < 2; ++ni)
            acc[mi][ni] = (f32x4_t){0.f, 0.f, 0.f, 0.f};

    auto STAGE = [&](int kt2, int buf) {
        const int off_ = kt2 >> 2, cic_ = kt2 & 3;
        const int kh_ = (off_ * 11) >> 5;                       // off/3
        const int doff_ = ((off_ + 31 * kh_) << 8) + (cic_ << 6);
        const int koff_ = (off_ << 8) + (cic_ << 6);
        #pragma unroll
        for (int i = 0; i < 2; ++i) {
            gload16(agp[i] + doff_, &Als[buf][(((i << 2) + wid) << 9)]);
            gload16(bgp[i] + koff_, &Bls[buf][(((i << 2) + wid) << 9)]);
        }
    };

    STAGE(0, 0);
    for (int kt = 0; kt < 36; ++kt) {
        const int cur = kt & 1;
        if (kt + 1 < 36) {
            STAGE(kt + 1, cur ^ 1);
            asm volatile("s_waitcnt vmcnt(4)" ::: "memory");
        } else {
            asm volatile("s_waitcnt vmcnt(0)" ::: "memory");
        }
        __builtin_amdgcn_s_barrier();
        asm volatile("" ::: "memory");
        #pragma unroll
        for (int kh = 0; kh < 2; ++kh) {
            const int sk = kh ? s1 : s0;
            bf16x8_t av[2], bv[2];
            #pragma unroll
            for (int mi = 0; mi < 2; ++mi)
                av[mi] = *(const bf16x8_t*)(&Als[cur][arow + (mi << 10) + sk]);
            #pragma unroll
            for (int ni = 0; ni < 2; ++ni)
                bv[ni] = *(const bf16x8_t*)(&Bls[cur][brow + (ni << 10) + sk]);
            #pragma unroll
            for (int mi = 0; mi < 2; ++mi)
                #pragma unroll
                for (int ni = 0; ni < 2; ++ni)
                    acc[mi][ni] = __builtin_amdgcn_mfma_f32_16x16x32_bf16(
                        av[mi], bv[ni], acc[mi][ni], 0, 0, 0);
        }
        __builtin_amdgcn_s_barrier();
        asm volatile("" ::: "memory");
    }

    const int cr = (lane >> 4) << 2;
    const int cc = lane & 15;
    #pragma unroll
    for (int ni = 0; ni < 2; ++ni) {
        const int co = co0 + (wn << 5) + (ni << 4) + cc;
        const float bb = bias[co];
        float ssum = 0.f, ssq = 0.f;
        #pragma unroll
        for (int mi = 0; mi < 2; ++mi) {
            const int n = m0 + (wm << 5) + (mi << 4) + cr;
            #pragma unroll
            for (int j = 0; j < 4; ++j) {
                float v = acc[mi][ni][j] + bb;
                if (RELU) v = fmaxf(v, 0.f);
                outp[(size_t)((b << 10) + n + j) * 256 + co] = f2b(v);
                if (STATS) { ssum += v; ssq += v * v; }
            }
        }
        if (STATS) {
            // lanes sharing co differ only in bits 4,5 of lane
            ssum += __shfl_xor(ssum, 16); ssum += __shfl_xor(ssum, 32);
            ssq  += __shfl_xor(ssq, 16);  ssq  += __shfl_xor(ssq, 32);
            if (lane < 16) {
                const int ch = (wn << 5) + (ni << 4) + cc;  // 0..63 local channel
                atomicAdd(&sstat[ch * 2], ssum);
                atomicAdd(&sstat[ch * 2 + 1], ssq);
            }
        }
    }
    if (STATS) {
        __syncthreads();
        if (tid < 64) {
            atomicAdd(&sums[co0 + tid], sstat[tid * 2]);
            atomicAdd(&sums[256 + co0 + tid], sstat[tid * 2 + 1]);
        }
    }
}

// bn apply; computes scale/shift from sums locally; writes padded Xp interior
template<bool TE>
__global__ __launch_bounds__(256) void bn_apply_T_k(
    const bf16* __restrict__ a, const float* __restrict__ sums,
    const float* __restrict__ g, const float* __restrict__ bb,
    const float* __restrict__ te, bf16* __restrict__ Xp)
{
    const int t = threadIdx.x;
    const int row = blockIdx.x * 8 + (t >> 5);
    const int c0 = (t & 31) << 3;
    const int b = row >> 10, n = row & 1023;
    const uint4 u = *(const uint4*)(a + (size_t)row * 256 + c0);
    const unsigned int w[4] = {u.x, u.y, u.z, u.w};
    float scv[8], shv[8];
    #pragma unroll
    for (int k = 0; k < 8; ++k) {
        const int c = c0 + k;
        const float m = sums[c] * (1.f / 16384.f);
        const float var = sums[256 + c] * (1.f / 16384.f) - m * m;
        const float sc = g[c] * rsqrtf(var + 1e-5f);
        scv[k] = sc;
        shv[k] = bb[c] - m * sc + (TE ? te[(b << 8) + c] : 0.f);
    }
    unsigned int o[4];
    #pragma unroll
    for (int k = 0; k < 4; ++k) {
        const float v0 = bits2f(w[k] & 0xffffu) * scv[2*k] + shv[2*k];
        const float v1 = __uint_as_float(w[k] & 0xffff0000u) * scv[2*k+1] + shv[2*k+1];
        o[k] = (unsigned int)f2bu(v0) | ((unsigned int)f2bu(v1) << 16);
    }
    const int p = ((n >> 5) + 1) * 34 + (n & 31) + 1;
    *(uint4*)(Xp + (size_t)(b * 1156 + p) * 256 + c0) = make_uint4(o[0], o[1], o[2], o[3]);
}

// Q|K projection
__global__ __launch_bounds__(256) void qk_mfma_k(
    const bf16* __restrict__ Yt, const bf16* __restrict__ WQK,
    const float* __restrict__ bq, const float* __restrict__ bk, bf16* __restrict__ QKb)
{
    const int b = blockIdx.x >> 4, m0 = (blockIdx.x & 15) << 6;
    const int tid = threadIdx.x, wid = tid >> 6, lane = tid & 63;
    const int n0w = m0 + (wid << 4);
    const bf16* arow = Yt + (size_t)((b << 10) + n0w + (lane & 15)) * 256 + ((lane >> 4) << 3);
    const int boff = ((lane >> 4) << 3);
    f32x4_t acc[4];
    #pragma unroll
    for (int ni = 0; ni < 4; ++ni) acc[ni] = (f32x4_t){0.f,0.f,0.f,0.f};
    for (int k0 = 0; k0 < 256; k0 += 32) {
        const bf16x8_t av = *(const bf16x8_t*)(arow + k0);
        #pragma unroll
        for (int ni = 0; ni < 4; ++ni) {
            const bf16x8_t bv = *(const bf16x8_t*)(WQK + (ni * 16 + (lane & 15)) * 256 + k0 + boff);
            acc[ni] = __builtin_amdgcn_mfma_f32_16x16x32_bf16(av, bv, acc[ni], 0, 0, 0);
        }
    }
    const int cr = (lane >> 4) << 2, cc = lane & 15;
    #pragma unroll
    for (int ni = 0; ni < 4; ++ni) {
        const int q = ni * 16 + cc;
        const float bias = (q < 32) ? bq[q] : bk[q - 32];
        #pragma unroll
        for (int j = 0; j < 4; ++j) {
            const int n = n0w + cr + j;
            QKb[(size_t)((b << 10) + n) * 64 + q] = f2b(acc[ni][j] + bias);
        }
    }
}

// V projection: Vb[b][v][n], 64x64 tile, dbuf, vmcnt(4). K=256 (4 steps).
__global__ __launch_bounds__(256, 4) void v_mfma_k(
    const bf16* __restrict__ WVb, const bf16* __restrict__ Yt,
    const float* __restrict__ bvp, bf16* __restrict__ Vb)
{
    __shared__ bf16 Als[2][64 * 64];
    __shared__ bf16 Bls[2][64 * 64];
    const int tid = threadIdx.x;
    const int wid = tid >> 6, lane = tid & 63;
    const int wm = wid >> 1, wn = wid & 1;
    const int blk = blockIdx.x;
    const int b = blk >> 6, vt = (blk >> 4) & 3, nt = blk & 15;
    const int v0 = vt << 6, n0 = nt << 6;

    const int lr = lane >> 3;
    const int sL8 = (((lane & 7) ^ lr) << 3);
    const bf16* agp[2]; const bf16* bgp[2];
    #pragma unroll
    for (int i = 0; i < 2; ++i) {
        const int r = (((i << 2) + wid) << 3) + lr;
        agp[i] = WVb + (size_t)(v0 + r) * 256 + sL8;
        bgp[i] = Yt + (size_t)((b << 10) + n0 + r) * 256 + sL8;
    }
    const int rsel = lane & 15;
    const int s0 = (((lane >> 4) ^ (lane & 7)) << 3);
    const int s1 = ((((lane >> 4) + 4) ^ (lane & 7)) << 3);
    const int arow = ((wm << 5) + rsel) << 6;
    const int brow = ((wn << 5) + rsel) << 6;

    f32x4_t acc[2][2];
    #pragma unroll
    for (int mi = 0; mi < 2; ++mi)
        #pragma unroll
        for (int ni = 0; ni < 2; ++ni)
            acc[mi][ni] = (f32x4_t){0.f,0.f,0.f,0.f};

    auto STAGE = [&](int koff, int buf) {
        #pragma unroll
        for (int i = 0; i < 2; ++i) {
            gload16(agp[i] + koff, &Als[buf][(((i << 2) + wid) << 9)]);
            gload16(bgp[i] + koff, &Bls[buf][(((i << 2) + wid) << 9)]);
        }
    };

    STAGE(0, 0);
    for (int kt = 0; kt < 4; ++kt) {
        const int cur = kt & 1;
        if (kt + 1 < 4) {
            STAGE((kt + 1) << 6, cur ^ 1);
            asm volatile("s_waitcnt vmcnt(4)" ::: "memory");
        } else {
            asm volatile("s_waitcnt vmcnt(0)" ::: "memory");
        }
        __builtin_amdgcn_s_barrier();
        asm volatile("" ::: "memory");
        #pragma unroll
        for (int kh = 0; kh < 2; ++kh) {
            const int sk = kh ? s1 : s0;
            bf16x8_t av[2], bv[2];
            #pragma unroll
            for (int mi = 0; mi < 2; ++mi)
                av[mi] = *(const bf16x8_t*)(&Als[cur][arow + (mi << 10) + sk]);
            #pragma unroll
            for (int ni = 0; ni < 2; ++ni)
                bv[ni] = *(const bf16x8_t*)(&Bls[cur][brow + (ni << 10) + sk]);
            #pragma unroll
            for (int mi = 0; mi < 2; ++mi)
                #pragma unroll
                for (int ni = 0; ni < 2; ++ni)
                    acc[mi][ni] = __builtin_amdgcn_mfma_f32_16x16x32_bf16(
                        av[mi], bv[ni], acc[mi][ni], 0, 0, 0);
        }
        __builtin_amdgcn_s_barrier();
        asm volatile("" ::: "memory");
    }

    const int cr = (lane >> 4) << 2, cc = lane & 15;
    #pragma unroll
    for (int mi = 0; mi < 2; ++mi) {
        #pragma unroll
        for (int j = 0; j < 4; ++j) {
            const int v = v0 + (wm << 5) + (mi << 4) + cr + j;
            const float bb = bvp[v];
            #pragma unroll
            for (int ni = 0; ni < 2; ++ni) {
                const int n = n0 + (wn << 5) + (ni << 4) + cc;
                Vb[(size_t)((b << 8) + v) * 1024 + n] = f2b(acc[mi][ni][j] + bb);
            }
        }
    }
}

// scores + softmax (unnormalized P, deferred 1/sum)
__global__ __launch_bounds__(256) void softmax_k(
    const bf16* __restrict__ QKb, bf16* __restrict__ P, float* __restrict__ invs)
{
    const int b = blockIdx.x >> 5, n0 = (blockIdx.x & 31) << 5;
    const int tid = threadIdx.x, wid = tid >> 6, lane = tid & 63;
    const int m0w = wid << 8;
    __shared__ float wred[4][32];

    const bf16* qbase = QKb + (size_t)((b << 10) + n0) * 64;
    const int koff = (lane >> 4) << 3;
    bf16x8_t qf[2];
    #pragma unroll
    for (int nt = 0; nt < 2; ++nt)
        qf[nt] = *(const bf16x8_t*)(qbase + (nt * 16 + (lane & 15)) * 64 + koff);
    const bf16* kbase = QKb + (size_t)(b << 10) * 64 + 32;

    float mx[2] = {-3.0e38f, -3.0e38f};
    for (int mi = 0; mi < 16; ++mi) {
        const bf16x8_t kf = *(const bf16x8_t*)(kbase + (m0w + mi * 16 + (lane & 15)) * 64 + koff);
        #pragma unroll
        for (int nt = 0; nt < 2; ++nt) {
            f32x4_t s = (f32x4_t){0.f,0.f,0.f,0.f};
            s = __builtin_amdgcn_mfma_f32_16x16x32_bf16(kf, qf[nt], s, 0, 0, 0);
            mx[nt] = fmaxf(mx[nt], fmaxf(fmaxf(s[0], s[1]), fmaxf(s[2], s[3])));
        }
    }
    #pragma unroll
    for (int nt = 0; nt < 2; ++nt) {
        mx[nt] = fmaxf(mx[nt], __shfl_xor(mx[nt], 16));
        mx[nt] = fmaxf(mx[nt], __shfl_xor(mx[nt], 32));
        if (lane < 16) wred[wid][nt * 16 + lane] = mx[nt];
    }
    __syncthreads();
    float rm[2];
    #pragma unroll
    for (int nt = 0; nt < 2; ++nt) {
        const int c = nt * 16 + (lane & 15);
        rm[nt] = fmaxf(fmaxf(wred[0][c], wred[1][c]), fmaxf(wred[2][c], wred[3][c]));
    }
    __syncthreads();

    float sm[2] = {0.f, 0.f};
    for (int mi = 0; mi < 16; ++mi) {
        const bf16x8_t kf = *(const bf16x8_t*)(kbase + (m0w + mi * 16 + (lane & 15)) * 64 + koff);
        #pragma unroll
        for (int nt = 0; nt < 2; ++nt) {
            f32x4_t s = (f32x4_t){0.f,0.f,0.f,0.f};
            s = __builtin_amdgcn_mfma_f32_16x16x32_bf16(kf, qf[nt], s, 0, 0, 0);
            const float p0 = __expf(s[0] - rm[nt]);
            const float p1 = __expf(s[1] - rm[nt]);
            const float p2 = __expf(s[2] - rm[nt]);
            const float p3 = __expf(s[3] - rm[nt]);
            sm[nt] += (p0 + p1) + (p2 + p3);
            uint2 u;
            u.x = (unsigned int)f2bu(p0) | ((unsigned int)f2bu(p1) << 16);
            u.y = (unsigned int)f2bu(p2) | ((unsigned int)f2bu(p3) << 16);
            const int n = n0 + nt * 16 + (lane & 15);
            const int m = m0w + mi * 16 + ((lane >> 4) << 2);
            *(uint2*)(P + (size_t)((b << 10) + n) * 1024 + m) = u;
        }
    }
    #pragma unroll
    for (int nt = 0; nt < 2; ++nt) {
        sm[nt] += __shfl_xor(sm[nt], 16);
        sm[nt] += __shfl_xor(sm[nt], 32);
        if (lane < 16) wred[wid][nt * 16 + lane] = sm[nt];
    }
    __syncthreads();
    if (tid < 32) {
        const float total = wred[0][tid] + wred[1][tid] + wred[2][tid] + wred[3][tid];
        invs[(b << 10) + n0 + tid] = 1.f / total;
    }
}

// PV + residual: 64x128 tile, dbuf, vmcnt(6). K=1024 (16 steps).
__global__ __launch_bounds__(256, 2) void pv_mfma_k(
    const bf16* __restrict__ Vb, const bf16* __restrict__ P,
    const float* __restrict__ invs, const bf16* __restrict__ Yt,
    const float* __restrict__ gamma, float* __restrict__ out)
{
    __shared__ bf16 Als[2][64 * 64];
    __shared__ bf16 Bls[2][128 * 64];
    const int tid = threadIdx.x;
    const int wid = tid >> 6, lane = tid & 63;
    const int wm = wid >> 1, wn = wid & 1;
    const int blk = blockIdx.x;
    const int b = blk >> 5, ct = (blk >> 3) & 3, nt = blk & 7;
    const int c0 = ct << 6, n0 = nt << 7;

    const int lr = lane >> 3;
    const int sL8 = (((lane & 7) ^ lr) << 3);
    const bf16* agp[2];
    #pragma unroll
    for (int i = 0; i < 2; ++i) {
        const int r = (((i << 2) + wid) << 3) + lr;
        agp[i] = Vb + (size_t)((b << 8) + c0 + r) * 1024 + sL8;
    }
    const bf16* bgp[4];
    #pragma unroll
    for (int i = 0; i < 4; ++i) {
        const int r = (((i << 2) + wid) << 3) + lr;
        bgp[i] = P + (size_t)((b << 10) + n0 + r) * 1024 + sL8;
    }
    const int rsel = lane & 15;
    const int s0 = (((lane >> 4) ^ (lane & 7)) << 3);
    const int s1 = ((((lane >> 4) + 4) ^ (lane & 7)) << 3);
    const int arow = ((wm << 5) + rsel) << 6;
    const int brow = ((wn << 6) + rsel) << 6;

    f32x4_t acc[2][4];
    #pragma unroll
    for (int mi = 0; mi < 2; ++mi)
        #pragma unroll
        for (int ni = 0; ni < 4; ++ni)
            acc[mi][ni] = (f32x4_t){0.f,0.f,0.f,0.f};

    auto STAGE = [&](int koff, int buf) {
        #pragma unroll
        for (int i = 0; i < 2; ++i)
            gload16(agp[i] + koff, &Als[buf][(((i << 2) + wid) << 9)]);
        #pragma unroll
        for (int i = 0; i < 4; ++i)
            gload16(bgp[i] + koff, &Bls[buf][(((i << 2) + wid) << 9)]);
    };

    STAGE(0, 0);
    for (int kt = 0; kt < 16; ++kt) {
        const int cur = kt & 1;
        if (kt + 1 < 16) {
            STAGE((kt + 1) << 6, cur ^ 1);
            asm volatile("s_waitcnt vmcnt(6)" ::: "memory");
        } else {
            asm volatile("s_waitcnt vmcnt(0)" ::: "memory");
        }
        __builtin_amdgcn_s_barrier();
        asm volatile("" ::: "memory");
        #pragma unroll
        for (int kh = 0; kh < 2; ++kh) {
            const int sk = kh ? s1 : s0;
            bf16x8_t av[2], bv[4];
            #pragma unroll
            for (int mi = 0; mi < 2; ++mi)
                av[mi] = *(const bf16x8_t*)(&Als[cur][arow + (mi << 10) + sk]);
            #pragma unroll
            for (int ni = 0; ni < 4; ++ni)
                bv[ni] = *(const bf16x8_t*)(&Bls[cur][brow + (ni << 10) + sk]);
            #pragma unroll
            for (int mi = 0; mi < 2; ++mi)
                #pragma unroll
                for (int ni = 0; ni < 4; ++ni)
                    acc[mi][ni] = __builtin_amdgcn_mfma_f32_16x16x32_bf16(
                        av[mi], bv[ni], acc[mi][ni], 0, 0, 0);
        }
        __builtin_amdgcn_s_barrier();
        asm volatile("" ::: "memory");
    }

    const float g = gamma[0];
    const int cr = (lane >> 4) << 2, cc = lane & 15;
    #pragma unroll
    for (int ni = 0; ni < 4; ++ni) {
        const int n = n0 + (wn << 6) + (ni << 4) + cc;
        const float gi = g * invs[(b << 10) + n];
        #pragma unroll
        for (int mi = 0; mi < 2; ++mi) {
            const int c = c0 + (wm << 5) + (mi << 4) + cr;
            const bf16* yp = Yt + (size_t)((b << 10) + n) * 256 + c;
            #pragma unroll
            for (int j = 0; j < 4; ++j)
                out[(size_t)((b << 8) + c + j) * 1024 + n] = gi * acc[mi][ni][j] + b2f(yp[j]);
        }
    }
}

// ---------------------------------------------------------------------------
// Workspace (base = ws+32K; ~52.7 MB):
//  te ws+0 (16K) | sums1 ws+16384 (2K) | sums2 ws+18432 (2K)
//  W3_1 [0) W3_2 [1179648) W3_3 [2359296)
//  Xp0 [3538944) Xp1 [13008896) Craw [22478848)
//  P [0, 32M) aliases dead conv bufs | Yt [33554432) QKb [41943040)
//  Vb [44040192) invs [52428800) WQK [52494336) WVb [52527104)
// ---------------------------------------------------------------------------
extern "C" void kernel_launch(void* const* d_in, const int* in_sizes, int n_in,
                              void* d_out, int out_size, void* d_ws, size_t ws_size,
                              hipStream_t stream)
{
    const float* x     = (const float*)d_in[0];
    const float* t     = (const float*)d_in[1];
    const float* w_t1  = (const float*)d_in[2];
    const float* b_t1  = (const float*)d_in[3];
    const float* w_t2  = (const float*)d_in[4];
    const float* b_t2  = (const float*)d_in[5];
    const float* w_c1  = (const float*)d_in[6];
    const float* b_c1  = (const float*)d_in[7];
    const float* w_c2  = (const float*)d_in[8];
    const float* b_c2  = (const float*)d_in[9];
    const float* w_tr  = (const float*)d_in[10];
    const float* b_tr  = (const float*)d_in[11];
    const float* bn1g  = (const float*)d_in[12];
    const float* bn1b  = (const float*)d_in[13];
    const float* bn2g  = (const float*)d_in[14];
    const float* bn2b  = (const float*)d_in[15];
    const float* wq    = (const float*)d_in[16];
    const float* bq    = (const float*)d_in[17];
    const float* wk    = (const float*)d_in[18];
    const float* bk    = (const float*)d_in[19];
    const float* wv    = (const float*)d_in[20];
    const float* bv    = (const float*)d_in[21];
    const float* gamma = (const float*)d_in[22];
    float* out = (float*)d_out;

    char* ws = (char*)d_ws;
    float* te    = (float*)(ws + 0);
    float* sums1 = (float*)(ws + 16384);
    float* sums2 = (float*)(ws + 18432);
    char* base = ws + 32768;
    bf16* W3_1 = (bf16*)(base);
    bf16* W3_2 = (bf16*)(base + 1179648);
    bf16* W3_3 = (bf16*)(base + 2359296);
    bf16* Xp0  = (bf16*)(base + 3538944);
    bf16* Xp1  = (bf16*)(base + 13008896);
    bf16* Craw = (bf16*)(base + 22478848);
    bf16* P    = (bf16*)(base);                    // 32 MB alias
    bf16* Yt   = (bf16*)(base + 33554432);
    bf16* QKb  = (bf16*)(base + 41943040);
    bf16* Vb   = (bf16*)(base + 44040192);
    float* invs= (float*)(base + 52428800);
    bf16* WQK  = (bf16*)(base + 52494336);
    bf16* WVb  = (bf16*)(base + 52527104);

    const unsigned int XP2_U32 = 2u * 16u * 1156u * 256u / 2u;   // Xp0+Xp1 contiguous

    zero_k<<<2048, 256, 0, stream>>>((unsigned int*)Xp0, XP2_U32);
    time_mlp_k<<<16, 256, 0, stream>>>(t, w_t1, b_t1, w_t2, b_t2, te);
    prep_w_all_k<<<768, 256, 0, stream>>>(w_c1, w_c2, w_tr, W3_1, W3_2, W3_3);
    prep_wqkv_k<<<320, 256, 0, stream>>>(wq, wk, wv, WQK, WVb);
    prep_x_k<<<1024, 256, 0, stream>>>(x, Xp0, sums1);   // also zeroes sums1+sums2

    conv_mfma_k<true, true><<<1024, 256, 0, stream>>>(Xp0, W3_1, b_c1, Craw, sums1);
    bn_apply_T_k<true><<<2048, 256, 0, stream>>>(Craw, sums1, bn1g, bn1b, te, Xp1);

    conv_mfma_k<true, true><<<1024, 256, 0, stream>>>(Xp1, W3_2, b_c2, Craw, sums2);
    bn_apply_T_k<false><<<2048, 256, 0, stream>>>(Craw, sums2, bn2g, bn2b, nullptr, Xp0);

    conv_mfma_k<false, false><<<1024, 256, 0, stream>>>(Xp0, W3_3, b_tr, Yt, nullptr);

    qk_mfma_k<<<256, 256, 0, stream>>>(Yt, WQK, bq, bk, QKb);
    v_mfma_k<<<1024, 256, 0, stream>>>(WVb, Yt, bv, Vb);
    softmax_k<<<512, 256, 0, stream>>>(QKb, P, invs);
    pv_mfma_k<<<512, 256, 0, stream>>>(Vb, P, invs, Yt, gamma, out);
}

// Round 8
// 169.736 us; speedup vs baseline: 25.5269x; 1.2016x over previous
//
#include <hip/hip_runtime.h>
#include <hip/hip_bf16.h>

using bf16 = __hip_bfloat16;

typedef __attribute__((ext_vector_type(8))) short bf16x8_t;
typedef __attribute__((ext_vector_type(4))) float f32x4_t;

__device__ __forceinline__ float b2f(bf16 x){ return __bfloat162float(x); }
__device__ __forceinline__ bf16  f2b(float x){ return __float2bfloat16(x); }
__device__ __forceinline__ unsigned short f2bu(float x){ bf16 h = __float2bfloat16(x); return *(unsigned short*)&h; }
__device__ __forceinline__ float bits2f(unsigned int lo16){ return __uint_as_float(lo16 << 16); }

__device__ __forceinline__ void gload16(const void* g, void* l) {
    __builtin_amdgcn_global_load_lds(
        (const __attribute__((address_space(1))) unsigned int*)g,
        (__attribute__((address_space(3))) unsigned int*)l, 16, 0, 0);
}

// ---------------------------------------------------------------------------
// Dims: B=16, C=256, H=W=32, N=1024, padded P=34x34=1156, Cq=32
// conv/v/pv GEMMs: 128x128 tile, BK=64, 512 thr (8 waves, 2Mx4N), 3-buf LDS,
// depth-2 prefetch with vmcnt(4), XCD-swizzled blockIdx (batch b -> XCD b%8).
// ---------------------------------------------------------------------------

__global__ void zero_k(unsigned int* __restrict__ p, unsigned int n) {
    for (unsigned int i = blockIdx.x * 256 + threadIdx.x; i < n; i += gridDim.x * 256) p[i] = 0u;
}

__global__ __launch_bounds__(256) void time_mlp_k(
    const float* __restrict__ t, const float* __restrict__ w1, const float* __restrict__ b1,
    const float* __restrict__ w2, const float* __restrict__ b2, float* __restrict__ te)
{
    const int b = blockIdx.x, j = threadIdx.x;
    __shared__ float tr[256], hid[256];
    tr[j] = t[(b << 8) + j];
    __syncthreads();
    float s = b1[j];
    const float* wp = w1 + j * 256;
    for (int k = 0; k < 256; ++k) s += tr[k] * wp[k];
    hid[j] = fmaxf(s, 0.f);
    __syncthreads();
    float s2 = b2[j];
    const float* wp2 = w2 + j * 256;
    for (int k = 0; k < 256; ++k) s2 += hid[k] * wp2[k];
    te[(b << 8) + j] = fmaxf(s2, 0.f);
}

// conv weights [co][ci][3][3] fp32 -> [co][off][ci] bf16
__global__ __launch_bounds__(256) void prep_w_all_k(
    const float* __restrict__ w1, const float* __restrict__ w2, const float* __restrict__ w3,
    bf16* __restrict__ W1, bf16* __restrict__ W2, bf16* __restrict__ W3o)
{
    __shared__ float ls[2304];
    const int t = threadIdx.x;
    const int co = blockIdx.x & 255;
    const int sel = blockIdx.x >> 8;
    const float* w = (sel == 0) ? w1 : (sel == 1) ? w2 : w3;
    bf16* dst = (sel == 0) ? W1 : (sel == 1) ? W2 : W3o;
    const float* src = w + (size_t)co * 2304;
    #pragma unroll
    for (int i = 0; i < 9; ++i) ls[t + (i << 8)] = src[t + (i << 8)];
    __syncthreads();
    #pragma unroll
    for (int off = 0; off < 9; ++off)
        dst[(size_t)(co * 9 + off) * 256 + t] = f2b(ls[t * 9 + off]);
}

__global__ __launch_bounds__(256) void prep_wqkv_k(
    const float* __restrict__ wq, const float* __restrict__ wk, const float* __restrict__ wv,
    bf16* __restrict__ WQK, bf16* __restrict__ WVb)
{
    const int r = blockIdx.x, c = threadIdx.x;
    if (r < 32)       WQK[r * 256 + c] = f2b(wq[r * 256 + c]);
    else if (r < 64)  WQK[r * 256 + c] = f2b(wk[(r - 32) * 256 + c]);
    else              WVb[(r - 64) * 256 + c] = f2b(wv[(r - 64) * 256 + c]);
}

// x fp32 [b][c][n] -> Xp bf16 [b][1156][c]; block 0 zeroes bn sums
__global__ __launch_bounds__(256) void prep_x_k(const float* __restrict__ x, bf16* __restrict__ Xp,
                                                float* __restrict__ sums)
{
    __shared__ float xs[64][65];
    const int t = threadIdx.x;
    if (blockIdx.x == 0) {
        sums[t] = 0.f; sums[t + 256] = 0.f; sums[t + 512] = 0.f; sums[t + 768] = 0.f;
    }
    const int b = blockIdx.x >> 6, ct = (blockIdx.x >> 4) & 3, nt = blockIdx.x & 15;
    const int c0 = ct << 6, n0 = nt << 6;
    {
        const int cl = t >> 2, nc = (t & 3) << 4;
        const float* src = x + (size_t)((b << 8) + c0 + cl) * 1024 + n0 + nc;
        #pragma unroll
        for (int j = 0; j < 16; j += 4) {
            const float4 v = *(const float4*)(src + j);
            xs[cl][nc + j] = v.x; xs[cl][nc + j + 1] = v.y;
            xs[cl][nc + j + 2] = v.z; xs[cl][nc + j + 3] = v.w;
        }
    }
    __syncthreads();
    {
        const int nl = t >> 2, cc = (t & 3) << 4;
        const int n = n0 + nl;
        const int p = ((n >> 5) + 1) * 34 + (n & 31) + 1;
        unsigned int u[8];
        #pragma unroll
        for (int k = 0; k < 8; ++k)
            u[k] = (unsigned int)f2bu(xs[cc + 2 * k][nl]) | ((unsigned int)f2bu(xs[cc + 2 * k + 1][nl]) << 16);
        bf16* dst = Xp + (size_t)(b * 1156 + p) * 256 + c0 + cc;
        *(uint4*)dst = make_uint4(u[0], u[1], u[2], u[3]);
        *(uint4*)(dst + 8) = make_uint4(u[4], u[5], u[6], u[7]);
    }
}

// ---- conv3x3 implicit GEMM: 128x128 tile, 512 thr, 3-buf depth-2 ----
template<bool RELU, bool STATS>
__global__ __launch_bounds__(512, 1) void conv_mfma_k(
    const bf16* __restrict__ Xp, const bf16* __restrict__ W3,
    const float* __restrict__ bias, bf16* __restrict__ outp, float* __restrict__ sums)
{
    __shared__ bf16 Als[3][128 * 64];
    __shared__ bf16 Bls[3][128 * 64];
    __shared__ float sstat[256];
    const int tid = threadIdx.x;
    const int wid = tid >> 6, lane = tid & 63;
    const int wm = wid >> 2, wn = wid & 3;
    // XCD swizzle: xcd = blk&7 serves batches {xcd, xcd+8}
    const int blk = blockIdx.x;
    const int xc = blk & 7, tt = blk >> 3;
    const int b = xc + ((tt >> 4) << 3);
    const int tile = tt & 15, mt = tile >> 1, nt = tile & 1;
    const int m0 = mt << 7, co0 = nt << 7;

    if (STATS && tid < 256) sstat[tid] = 0.f;

    const int lrow = tid >> 3;                       // 0..63
    const int sL8 = (((tid & 7) ^ (lrow & 7)) << 3); // pre-swizzled global k-slot

    const bf16* agp[2]; const bf16* bgp[2];
    #pragma unroll
    for (int i = 0; i < 2; ++i) {
        const int r = (i << 6) + lrow;
        const int n = m0 + r;
        const int pb = (n >> 5) * 34 + (n & 31);
        agp[i] = Xp + (size_t)(b * 1156 + pb) * 256 + sL8;
        bgp[i] = W3 + (size_t)(co0 + r) * 2304 + sL8;
    }

    const int rsel = lane & 15;
    const int s0 = (((lane >> 4) ^ (lane & 7)) << 3);
    const int s1 = ((((lane >> 4) + 4) ^ (lane & 7)) << 3);
    const int abase = ((wm << 6) + rsel) << 6;
    const int bbase = ((wn << 5) + rsel) << 6;

    f32x4_t acc[4][2];
    #pragma unroll
    for (int mi = 0; mi < 4; ++mi)
        #pragma unroll
        for (int ni = 0; ni < 2; ++ni)
            acc[mi][ni] = (f32x4_t){0.f, 0.f, 0.f, 0.f};

    auto STAGE = [&](int kt2, int buf) {
        const int off_ = kt2 >> 2, cic_ = kt2 & 3;
        const int kh_ = (off_ * 11) >> 5;                       // off/3 (off<=8)
        const int doff_ = ((off_ + 31 * kh_) << 8) + (cic_ << 6);
        const int koff_ = (off_ << 8) + (cic_ << 6);
        #pragma unroll
        for (int i = 0; i < 2; ++i) {
            gload16(agp[i] + doff_, &Als[buf][((i << 6) + (wid << 3)) << 6]);
            gload16(bgp[i] + koff_, &Bls[buf][((i << 6) + (wid << 3)) << 6]);
        }
    };

    STAGE(0, 0); STAGE(1, 1);
    for (int kt = 0; kt < 36; ++kt) {
        if (kt < 35) asm volatile("s_waitcnt vmcnt(4)" ::: "memory");
        else         asm volatile("s_waitcnt vmcnt(0)" ::: "memory");
        __builtin_amdgcn_s_barrier();
        asm volatile("" ::: "memory");
        const int cur = kt % 3;
        #pragma unroll
        for (int kh = 0; kh < 2; ++kh) {
            const int sk = kh ? s1 : s0;
            bf16x8_t av[4], bv[2];
            #pragma unroll
            for (int mi = 0; mi < 4; ++mi)
                av[mi] = *(const bf16x8_t*)(&Als[cur][abase + (mi << 10) + sk]);
            #pragma unroll
            for (int ni = 0; ni < 2; ++ni)
                bv[ni] = *(const bf16x8_t*)(&Bls[cur][bbase + (ni << 10) + sk]);
            #pragma unroll
            for (int mi = 0; mi < 4; ++mi)
                #pragma unroll
                for (int ni = 0; ni < 2; ++ni)
                    acc[mi][ni] = __builtin_amdgcn_mfma_f32_16x16x32_bf16(
                        av[mi], bv[ni], acc[mi][ni], 0, 0, 0);
        }
        if (kt + 2 < 36) STAGE(kt + 2, (kt + 2) % 3);
    }

    const int cr = (lane >> 4) << 2;
    const int cc = lane & 15;
    #pragma unroll
    for (int ni = 0; ni < 2; ++ni) {
        const int co = co0 + (wn << 5) + (ni << 4) + cc;
        const float bb = bias[co];
        float ssum = 0.f, ssq = 0.f;
        #pragma unroll
        for (int mi = 0; mi < 4; ++mi) {
            const int n = m0 + (wm << 6) + (mi << 4) + cr;
            #pragma unroll
            for (int j = 0; j < 4; ++j) {
                float v = acc[mi][ni][j] + bb;
                if (RELU) v = fmaxf(v, 0.f);
                outp[(size_t)((b << 10) + n + j) * 256 + co] = f2b(v);
                if (STATS) { ssum += v; ssq += v * v; }
            }
        }
        if (STATS) {
            ssum += __shfl_xor(ssum, 16); ssum += __shfl_xor(ssum, 32);
            ssq  += __shfl_xor(ssq, 16);  ssq  += __shfl_xor(ssq, 32);
            if (lane < 16) {
                const int ch = (wn << 5) + (ni << 4) + cc;   // 0..127
                atomicAdd(&sstat[ch * 2], ssum);
                atomicAdd(&sstat[ch * 2 + 1], ssq);
            }
        }
    }
    if (STATS) {
        __syncthreads();
        if (tid < 128) {
            atomicAdd(&sums[co0 + tid], sstat[tid * 2]);
            atomicAdd(&sums[256 + co0 + tid], sstat[tid * 2 + 1]);
        }
    }
}

// bn apply; computes scale/shift from sums locally; writes padded Xp interior
template<bool TE>
__global__ __launch_bounds__(256) void bn_apply_T_k(
    const bf16* __restrict__ a, const float* __restrict__ sums,
    const float* __restrict__ g, const float* __restrict__ bb,
    const float* __restrict__ te, bf16* __restrict__ Xp)
{
    const int t = threadIdx.x;
    const int row = blockIdx.x * 8 + (t >> 5);
    const int c0 = (t & 31) << 3;
    const int b = row >> 10, n = row & 1023;
    const uint4 u = *(const uint4*)(a + (size_t)row * 256 + c0);
    const unsigned int w[4] = {u.x, u.y, u.z, u.w};
    float scv[8], shv[8];
    #pragma unroll
    for (int k = 0; k < 8; ++k) {
        const int c = c0 + k;
        const float m = sums[c] * (1.f / 16384.f);
        const float var = sums[256 + c] * (1.f / 16384.f) - m * m;
        const float sc = g[c] * rsqrtf(var + 1e-5f);
        scv[k] = sc;
        shv[k] = bb[c] - m * sc + (TE ? te[(b << 8) + c] : 0.f);
    }
    unsigned int o[4];
    #pragma unroll
    for (int k = 0; k < 4; ++k) {
        const float v0 = bits2f(w[k] & 0xffffu) * scv[2*k] + shv[2*k];
        const float v1 = __uint_as_float(w[k] & 0xffff0000u) * scv[2*k+1] + shv[2*k+1];
        o[k] = (unsigned int)f2bu(v0) | ((unsigned int)f2bu(v1) << 16);
    }
    const int p = ((n >> 5) + 1) * 34 + (n & 31) + 1;
    *(uint4*)(Xp + (size_t)(b * 1156 + p) * 256 + c0) = make_uint4(o[0], o[1], o[2], o[3]);
}

// Q|K projection
__global__ __launch_bounds__(256) void qk_mfma_k(
    const bf16* __restrict__ Yt, const bf16* __restrict__ WQK,
    const float* __restrict__ bq, const float* __restrict__ bk, bf16* __restrict__ QKb)
{
    const int b = blockIdx.x >> 4, m0 = (blockIdx.x & 15) << 6;
    const int tid = threadIdx.x, wid = tid >> 6, lane = tid & 63;
    const int n0w = m0 + (wid << 4);
    const bf16* arow = Yt + (size_t)((b << 10) + n0w + (lane & 15)) * 256 + ((lane >> 4) << 3);
    const int boff = ((lane >> 4) << 3);
    f32x4_t acc[4];
    #pragma unroll
    for (int ni = 0; ni < 4; ++ni) acc[ni] = (f32x4_t){0.f,0.f,0.f,0.f};
    for (int k0 = 0; k0 < 256; k0 += 32) {
        const bf16x8_t av = *(const bf16x8_t*)(arow + k0);
        #pragma unroll
        for (int ni = 0; ni < 4; ++ni) {
            const bf16x8_t bv = *(const bf16x8_t*)(WQK + (ni * 16 + (lane & 15)) * 256 + k0 + boff);
            acc[ni] = __builtin_amdgcn_mfma_f32_16x16x32_bf16(av, bv, acc[ni], 0, 0, 0);
        }
    }
    const int cr = (lane >> 4) << 2, cc = lane & 15;
    #pragma unroll
    for (int ni = 0; ni < 4; ++ni) {
        const int q = ni * 16 + cc;
        const float bias = (q < 32) ? bq[q] : bk[q - 32];
        #pragma unroll
        for (int j = 0; j < 4; ++j) {
            const int n = n0w + cr + j;
            QKb[(size_t)((b << 10) + n) * 64 + q] = f2b(acc[ni][j] + bias);
        }
    }
}

// V projection: Vb[b][v][n], 128x128 tile, 512 thr, K=256 (4 steps)
__global__ __launch_bounds__(512, 1) void v_mfma_k(
    const bf16* __restrict__ WVb, const bf16* __restrict__ Yt,
    const float* __restrict__ bvp, bf16* __restrict__ Vb)
{
    __shared__ bf16 Als[3][128 * 64];
    __shared__ bf16 Bls[3][128 * 64];
    const int tid = threadIdx.x;
    const int wid = tid >> 6, lane = tid & 63;
    const int wm = wid >> 2, wn = wid & 3;
    const int blk = blockIdx.x;
    const int xc = blk & 7, tt = blk >> 3;
    const int b = xc + ((tt >> 4) << 3);
    const int tile = tt & 15, vt = tile >> 3, nt = tile & 7;
    const int v0 = vt << 7, n0 = nt << 7;

    const int lrow = tid >> 3;
    const int sL8 = (((tid & 7) ^ (lrow & 7)) << 3);
    const bf16* agp[2]; const bf16* bgp[2];
    #pragma unroll
    for (int i = 0; i < 2; ++i) {
        const int r = (i << 6) + lrow;
        agp[i] = WVb + (size_t)(v0 + r) * 256 + sL8;
        bgp[i] = Yt + (size_t)((b << 10) + n0 + r) * 256 + sL8;
    }
    const int rsel = lane & 15;
    const int s0 = (((lane >> 4) ^ (lane & 7)) << 3);
    const int s1 = ((((lane >> 4) + 4) ^ (lane & 7)) << 3);
    const int abase = ((wm << 6) + rsel) << 6;
    const int bbase = ((wn << 5) + rsel) << 6;

    f32x4_t acc[4][2];
    #pragma unroll
    for (int mi = 0; mi < 4; ++mi)
        #pragma unroll
        for (int ni = 0; ni < 2; ++ni)
            acc[mi][ni] = (f32x4_t){0.f,0.f,0.f,0.f};

    auto STAGE = [&](int kt2, int buf) {
        const int koff = kt2 << 6;
        #pragma unroll
        for (int i = 0; i < 2; ++i) {
            gload16(agp[i] + koff, &Als[buf][((i << 6) + (wid << 3)) << 6]);
            gload16(bgp[i] + koff, &Bls[buf][((i << 6) + (wid << 3)) << 6]);
        }
    };

    STAGE(0, 0); STAGE(1, 1);
    for (int kt = 0; kt < 4; ++kt) {
        if (kt < 3) asm volatile("s_waitcnt vmcnt(4)" ::: "memory");
        else        asm volatile("s_waitcnt vmcnt(0)" ::: "memory");
        __builtin_amdgcn_s_barrier();
        asm volatile("" ::: "memory");
        const int cur = kt % 3;
        #pragma unroll
        for (int kh = 0; kh < 2; ++kh) {
            const int sk = kh ? s1 : s0;
            bf16x8_t av[4], bv[2];
            #pragma unroll
            for (int mi = 0; mi < 4; ++mi)
                av[mi] = *(const bf16x8_t*)(&Als[cur][abase + (mi << 10) + sk]);
            #pragma unroll
            for (int ni = 0; ni < 2; ++ni)
                bv[ni] = *(const bf16x8_t*)(&Bls[cur][bbase + (ni << 10) + sk]);
            #pragma unroll
            for (int mi = 0; mi < 4; ++mi)
                #pragma unroll
                for (int ni = 0; ni < 2; ++ni)
                    acc[mi][ni] = __builtin_amdgcn_mfma_f32_16x16x32_bf16(
                        av[mi], bv[ni], acc[mi][ni], 0, 0, 0);
        }
        if (kt + 2 < 4) STAGE(kt + 2, (kt + 2) % 3);
    }

    const int cr = (lane >> 4) << 2, cc = lane & 15;
    #pragma unroll
    for (int mi = 0; mi < 4; ++mi) {
        #pragma unroll
        for (int j = 0; j < 4; ++j) {
            const int v = v0 + (wm << 6) + (mi << 4) + cr + j;
            const float bb = bvp[v];
            #pragma unroll
            for (int ni = 0; ni < 2; ++ni) {
                const int n = n0 + (wn << 5) + (ni << 4) + cc;
                Vb[(size_t)((b << 8) + v) * 1024 + n] = f2b(acc[mi][ni][j] + bb);
            }
        }
    }
}

// scores + softmax (unnormalized P, deferred 1/sum)
__global__ __launch_bounds__(256) void softmax_k(
    const bf16* __restrict__ QKb, bf16* __restrict__ P, float* __restrict__ invs)
{
    const int b = blockIdx.x >> 5, n0 = (blockIdx.x & 31) << 5;
    const int tid = threadIdx.x, wid = tid >> 6, lane = tid & 63;
    const int m0w = wid << 8;
    __shared__ float wred[4][32];

    const bf16* qbase = QKb + (size_t)((b << 10) + n0) * 64;
    const int koff = (lane >> 4) << 3;
    bf16x8_t qf[2];
    #pragma unroll
    for (int nt = 0; nt < 2; ++nt)
        qf[nt] = *(const bf16x8_t*)(qbase + (nt * 16 + (lane & 15)) * 64 + koff);
    const bf16* kbase = QKb + (size_t)(b << 10) * 64 + 32;

    float mx[2] = {-3.0e38f, -3.0e38f};
    for (int mi = 0; mi < 16; ++mi) {
        const bf16x8_t kf = *(const bf16x8_t*)(kbase + (m0w + mi * 16 + (lane & 15)) * 64 + koff);
        #pragma unroll
        for (int nt = 0; nt < 2; ++nt) {
            f32x4_t s = (f32x4_t){0.f,0.f,0.f,0.f};
            s = __builtin_amdgcn_mfma_f32_16x16x32_bf16(kf, qf[nt], s, 0, 0, 0);
            mx[nt] = fmaxf(mx[nt], fmaxf(fmaxf(s[0], s[1]), fmaxf(s[2], s[3])));
        }
    }
    #pragma unroll
    for (int nt = 0; nt < 2; ++nt) {
        mx[nt] = fmaxf(mx[nt], __shfl_xor(mx[nt], 16));
        mx[nt] = fmaxf(mx[nt], __shfl_xor(mx[nt], 32));
        if (lane < 16) wred[wid][nt * 16 + lane] = mx[nt];
    }
    __syncthreads();
    float rm[2];
    #pragma unroll
    for (int nt = 0; nt < 2; ++nt) {
        const int c = nt * 16 + (lane & 15);
        rm[nt] = fmaxf(fmaxf(wred[0][c], wred[1][c]), fmaxf(wred[2][c], wred[3][c]));
    }
    __syncthreads();

    float sm[2] = {0.f, 0.f};
    for (int mi = 0; mi < 16; ++mi) {
        const bf16x8_t kf = *(const bf16x8_t*)(kbase + (m0w + mi * 16 + (lane & 15)) * 64 + koff);
        #pragma unroll
        for (int nt = 0; nt < 2; ++nt) {
            f32x4_t s = (f32x4_t){0.f,0.f,0.f,0.f};
            s = __builtin_amdgcn_mfma_f32_16x16x32_bf16(kf, qf[nt], s, 0, 0, 0);
            const float p0 = __expf(s[0] - rm[nt]);
            const float p1 = __expf(s[1] - rm[nt]);
            const float p2 = __expf(s[2] - rm[nt]);
            const float p3 = __expf(s[3] - rm[nt]);
            sm[nt] += (p0 + p1) + (p2 + p3);
            uint2 u;
            u.x = (unsigned int)f2bu(p0) | ((unsigned int)f2bu(p1) << 16);
            u.y = (unsigned int)f2bu(p2) | ((unsigned int)f2bu(p3) << 16);
            const int n = n0 + nt * 16 + (lane & 15);
            const int m = m0w + mi * 16 + ((lane >> 4) << 2);
            *(uint2*)(P + (size_t)((b << 10) + n) * 1024 + m) = u;
        }
    }
    #pragma unroll
    for (int nt = 0; nt < 2; ++nt) {
        sm[nt] += __shfl_xor(sm[nt], 16);
        sm[nt] += __shfl_xor(sm[nt], 32);
        if (lane < 16) wred[wid][nt * 16 + lane] = sm[nt];
    }
    __syncthreads();
    if (tid < 32) {
        const float total = wred[0][tid] + wred[1][tid] + wred[2][tid] + wred[3][tid];
        invs[(b << 10) + n0 + tid] = 1.f / total;
    }
}

// PV + residual: 128x128 tile, 512 thr, K=1024 (16 steps)
__global__ __launch_bounds__(512, 1) void pv_mfma_k(
    const bf16* __restrict__ Vb, const bf16* __restrict__ P,
    const float* __restrict__ invs, const bf16* __restrict__ Yt,
    const float* __restrict__ gamma, float* __restrict__ out)
{
    __shared__ bf16 Als[3][128 * 64];
    __shared__ bf16 Bls[3][128 * 64];
    const int tid = threadIdx.x;
    const int wid = tid >> 6, lane = tid & 63;
    const int wm = wid >> 2, wn = wid & 3;
    const int blk = blockIdx.x;
    const int xc = blk & 7, tt = blk >> 3;
    const int b = xc + ((tt >> 4) << 3);
    const int tile = tt & 15, ct = tile >> 3, nt = tile & 7;
    const int c0 = ct << 7, n0 = nt << 7;

    const int lrow = tid >> 3;
    const int sL8 = (((tid & 7) ^ (lrow & 7)) << 3);
    const bf16* agp[2]; const bf16* bgp[2];
    #pragma unroll
    for (int i = 0; i < 2; ++i) {
        const int r = (i << 6) + lrow;
        agp[i] = Vb + (size_t)((b << 8) + c0 + r) * 1024 + sL8;
        bgp[i] = P + (size_t)((b << 10) + n0 + r) * 1024 + sL8;
    }
    const int rsel = lane & 15;
    const int s0 = (((lane >> 4) ^ (lane & 7)) << 3);
    const int s1 = ((((lane >> 4) + 4) ^ (lane & 7)) << 3);
    const int abase = ((wm << 6) + rsel) << 6;
    const int bbase = ((wn << 5) + rsel) << 6;

    f32x4_t acc[4][2];
    #pragma unroll
    for (int mi = 0; mi < 4; ++mi)
        #pragma unroll
        for (int ni = 0; ni < 2; ++ni)
            acc[mi][ni] = (f32x4_t){0.f,0.f,0.f,0.f};

    auto STAGE = [&](int kt2, int buf) {
        const int koff = kt2 << 6;
        #pragma unroll
        for (int i = 0; i < 2; ++i) {
            gload16(agp[i] + koff, &Als[buf][((i << 6) + (wid << 3)) << 6]);
            gload16(bgp[i] + koff, &Bls[buf][((i << 6) + (wid << 3)) << 6]);
        }
    };

    STAGE(0, 0); STAGE(1, 1);
    for (int kt = 0; kt < 16; ++kt) {
        if (kt < 15) asm volatile("s_waitcnt vmcnt(4)" ::: "memory");
        else         asm volatile("s_waitcnt vmcnt(0)" ::: "memory");
        __builtin_amdgcn_s_barrier();
        asm volatile("" ::: "memory");
        const int cur = kt % 3;
        #pragma unroll
        for (int kh = 0; kh < 2; ++kh) {
            const int sk = kh ? s1 : s0;
            bf16x8_t av[4], bv[2];
            #pragma unroll
            for (int mi = 0; mi < 4; ++mi)
                av[mi] = *(const bf16x8_t*)(&Als[cur][abase + (mi << 10) + sk]);
            #pragma unroll
            for (int ni = 0; ni < 2; ++ni)
                bv[ni] = *(const bf16x8_t*)(&Bls[cur][bbase + (ni << 10) + sk]);
            #pragma unroll
            for (int mi = 0; mi < 4; ++mi)
                #pragma unroll
                for (int ni = 0; ni < 2; ++ni)
                    acc[mi][ni] = __builtin_amdgcn_mfma_f32_16x16x32_bf16(
                        av[mi], bv[ni], acc[mi][ni], 0, 0, 0);
        }
        if (kt + 2 < 16) STAGE(kt + 2, (kt + 2) % 3);
    }

    const float g = gamma[0];
    const int cr = (lane >> 4) << 2, cc = lane & 15;
    #pragma unroll
    for (int ni = 0; ni < 2; ++ni) {
        const int n = n0 + (wn << 5) + (ni << 4) + cc;
        const float gi = g * invs[(b << 10) + n];
        #pragma unroll
        for (int mi = 0; mi < 4; ++mi) {
            const int c = c0 + (wm << 6) + (mi << 4) + cr;
            const bf16* yp = Yt + (size_t)((b << 10) + n) * 256 + c;
            #pragma unroll
            for (int j = 0; j < 4; ++j)
                out[(size_t)((b << 8) + c + j) * 1024 + n] = gi * acc[mi][ni][j] + b2f(yp[j]);
        }
    }
}

// ---------------------------------------------------------------------------
// Workspace (base = ws+32K; ~52.7 MB): same layout as round 7
// ---------------------------------------------------------------------------
extern "C" void kernel_launch(void* const* d_in, const int* in_sizes, int n_in,
                              void* d_out, int out_size, void* d_ws, size_t ws_size,
                              hipStream_t stream)
{
    const float* x     = (const float*)d_in[0];
    const float* t     = (const float*)d_in[1];
    const float* w_t1  = (const float*)d_in[2];
    const float* b_t1  = (const float*)d_in[3];
    const float* w_t2  = (const float*)d_in[4];
    const float* b_t2  = (const float*)d_in[5];
    const float* w_c1  = (const float*)d_in[6];
    const float* b_c1  = (const float*)d_in[7];
    const float* w_c2  = (const float*)d_in[8];
    const float* b_c2  = (const float*)d_in[9];
    const float* w_tr  = (const float*)d_in[10];
    const float* b_tr  = (const float*)d_in[11];
    const float* bn1g  = (const float*)d_in[12];
    const float* bn1b  = (const float*)d_in[13];
    const float* bn2g  = (const float*)d_in[14];
    const float* bn2b  = (const float*)d_in[15];
    const float* wq    = (const float*)d_in[16];
    const float* bq    = (const float*)d_in[17];
    const float* wk    = (const float*)d_in[18];
    const float* bk    = (const float*)d_in[19];
    const float* wv    = (const float*)d_in[20];
    const float* bv    = (const float*)d_in[21];
    const float* gamma = (const float*)d_in[22];
    float* out = (float*)d_out;

    char* ws = (char*)d_ws;
    float* te    = (float*)(ws + 0);
    float* sums1 = (float*)(ws + 16384);
    float* sums2 = (float*)(ws + 18432);
    char* base = ws + 32768;
    bf16* W3_1 = (bf16*)(base);
    bf16* W3_2 = (bf16*)(base + 1179648);
    bf16* W3_3 = (bf16*)(base + 2359296);
    bf16* Xp0  = (bf16*)(base + 3538944);
    bf16* Xp1  = (bf16*)(base + 13008896);
    bf16* Craw = (bf16*)(base + 22478848);
    bf16* P    = (bf16*)(base);                    // 32 MB alias
    bf16* Yt   = (bf16*)(base + 33554432);
    bf16* QKb  = (bf16*)(base + 41943040);
    bf16* Vb   = (bf16*)(base + 44040192);
    float* invs= (float*)(base + 52428800);
    bf16* WQK  = (bf16*)(base + 52494336);
    bf16* WVb  = (bf16*)(base + 52527104);

    const unsigned int XP2_U32 = 2u * 16u * 1156u * 256u / 2u;

    zero_k<<<2048, 256, 0, stream>>>((unsigned int*)Xp0, XP2_U32);
    time_mlp_k<<<16, 256, 0, stream>>>(t, w_t1, b_t1, w_t2, b_t2, te);
    prep_w_all_k<<<768, 256, 0, stream>>>(w_c1, w_c2, w_tr, W3_1, W3_2, W3_3);
    prep_wqkv_k<<<320, 256, 0, stream>>>(wq, wk, wv, WQK, WVb);
    prep_x_k<<<1024, 256, 0, stream>>>(x, Xp0, sums1);

    conv_mfma_k<true, true><<<256, 512, 0, stream>>>(Xp0, W3_1, b_c1, Craw, sums1);
    bn_apply_T_k<true><<<2048, 256, 0, stream>>>(Craw, sums1, bn1g, bn1b, te, Xp1);

    conv_mfma_k<true, true><<<256, 512, 0, stream>>>(Xp1, W3_2, b_c2, Craw, sums2);
    bn_apply_T_k<false><<<2048, 256, 0, stream>>>(Craw, sums2, bn2g, bn2b, nullptr, Xp0);

    conv_mfma_k<false, false><<<256, 512, 0, stream>>>(Xp0, W3_3, b_tr, Yt, nullptr);

    qk_mfma_k<<<256, 256, 0, stream>>>(Yt, WQK, bq, bk, QKb);
    v_mfma_k<<<256, 512, 0, stream>>>(WVb, Yt, bv, Vb);
    softmax_k<<<512, 256, 0, stream>>>(QKb, P, invs);
    pv_mfma_k<<<256, 512, 0, stream>>>(Vb, P, invs, Yt, gamma, out);
}